// Round 2
// baseline (13336.458 us; speedup 1.0000x reference)
//
#include <hip/hip_runtime.h>
#include <math.h>

// ---------------------------------------------------------------------------
// AttentiveEncoderDecoderNetwork: 6 convs -> contextual attention -> 2 convs
// Round 1: two workspace plans, branch on ws_size (deterministic).
//  Path A (ws >= 491 MB): materialize S fp32 (round-0 structure).
//  Path C (ws >= 207 MB): Gram-trick norm + striped fused exp/PV, no S.
// ---------------------------------------------------------------------------

#define TILE 16

// Direct conv, reflect padding, LDS-staged input tile, 8 out-channels/thread.
// ACT: 0 = relu, 1 = elu
template<int KS, int STRIDE, int ACT, int CHUNK>
__global__ __launch_bounds__(256)
void conv2d_kernel(const float* __restrict__ in, const float* __restrict__ wgt,
                   const float* __restrict__ bias, float* __restrict__ out,
                   int Cin, int Cout, int H, int W, int Ho, int Wo, int pad)
{
    constexpr int TIN = (TILE - 1) * STRIDE + KS;
    constexpr int OCPT = 8;
    __shared__ float sIn[CHUNK][TIN][TIN + 1];

    const int tx = threadIdx.x & 15;
    const int ty = threadIdx.x >> 4;
    const int ox0 = blockIdx.x * TILE;
    const int oy0 = blockIdx.y * TILE;
    const int oc0 = blockIdx.z * OCPT;

    float acc[OCPT];
#pragma unroll
    for (int o = 0; o < OCPT; ++o) acc[o] = 0.f;

    const int ksq = KS * KS;
    for (int c0 = 0; c0 < Cin; c0 += CHUNK) {
        for (int idx = threadIdx.x; idx < CHUNK * TIN * TIN; idx += 256) {
            int c   = idx / (TIN * TIN);
            int rem = idx - c * (TIN * TIN);
            int y   = rem / TIN;
            int x   = rem - y * TIN;
            int gy = oy0 * STRIDE - pad + y;
            int gx = ox0 * STRIDE - pad + x;
            gy = gy < 0 ? -gy : (gy >= H ? 2 * H - 2 - gy : gy);
            gx = gx < 0 ? -gx : (gx >= W ? 2 * W - 2 - gx : gx);
            sIn[c][y][x] = in[(size_t)(c0 + c) * H * W + (size_t)gy * W + gx];
        }
        __syncthreads();
#pragma unroll 2
        for (int c = 0; c < CHUNK; ++c) {
            const float* wp = wgt + ((size_t)oc0 * Cin + (size_t)(c0 + c)) * ksq;
#pragma unroll
            for (int ky = 0; ky < KS; ++ky) {
#pragma unroll
                for (int kx = 0; kx < KS; ++kx) {
                    float v = sIn[c][ty * STRIDE + ky][tx * STRIDE + kx];
#pragma unroll
                    for (int o = 0; o < OCPT; ++o)
                        acc[o] = fmaf(v, wp[(size_t)o * Cin * ksq + ky * KS + kx], acc[o]);
                }
            }
        }
        __syncthreads();
    }
    const int oy = oy0 + ty, ox = ox0 + tx;
#pragma unroll
    for (int o = 0; o < OCPT; ++o) {
        float v = acc[o] + bias[oc0 + o];
        if (ACT == 0) v = v > 0.f ? v : 0.f;
        else          v = v > 0.f ? v : expm1f(v);
        out[(size_t)(oc0 + o) * Ho * Wo + (size_t)oy * Wo + ox] = v;
    }
}

__global__ void downsample_mask_kernel(const float* __restrict__ h,
                                       const float* __restrict__ mask,
                                       float* __restrict__ fg, float* __restrict__ bg)
{
    int idx = blockIdx.x * 256 + threadIdx.x; // 128*96*96
    if (idx >= 128 * 96 * 96) return;
    int x = idx % 96;
    int y = (idx / 96) % 96;
    int c = idx / (96 * 96);
    float v = h[(size_t)c * 192 * 192 + (size_t)(2 * y) * 192 + 2 * x];
    float m = mask[(size_t)(2 * y) * 192 + 2 * x];
    bg[idx] = v;
    fg[idx] = v * m;
}

__global__ void patches_kernel(const float* __restrict__ src, float* __restrict__ dst)
{
    int idx = blockIdx.x * 256 + threadIdx.x; // 1152*9216
    if (idx >= 1152 * 9216) return;
    int p = idx % 9216;
    int k = idx / 9216;
    int c = k / 9;
    int t = k - c * 9;
    int dy = t / 3, dx = t % 3;
    int y = p / 96, x = p % 96;
    int sy = y + dy - 1, sx = x + dx - 1;
    float v = 0.f;
    if (sy >= 0 && sy < 96 && sx >= 0 && sx < 96)
        v = src[(size_t)c * 9216 + sy * 96 + sx];
    dst[idx] = v;
}

// C[p][q] = sum_k A[k][p] * B[k][q]
__global__ __launch_bounds__(256)
void gemm_tn_kernel(const float* __restrict__ A, const float* __restrict__ B,
                    float* __restrict__ C, int P, int Q, int K)
{
    __shared__ float As[8][128];
    __shared__ float Bs[8][128];
    const int tid = threadIdx.x;
    const int bm = blockIdx.y * 128;
    const int bn = blockIdx.x * 128;
    const int lr = tid >> 5;
    const int lc = (tid & 31) << 2;
    const int tx = tid & 15, ty = tid >> 4;
    float acc[8][8] = {};
    for (int k0 = 0; k0 < K; k0 += 8) {
        *(float4*)(&As[lr][lc]) = *(const float4*)(&A[(size_t)(k0 + lr) * P + bm + lc]);
        *(float4*)(&Bs[lr][lc]) = *(const float4*)(&B[(size_t)(k0 + lr) * Q + bn + lc]);
        __syncthreads();
#pragma unroll
        for (int kk = 0; kk < 8; ++kk) {
            float a[8], b[8];
            *(float4*)(a)     = *(float4*)(&As[kk][ty * 8]);
            *(float4*)(a + 4) = *(float4*)(&As[kk][ty * 8 + 4]);
            *(float4*)(b)     = *(float4*)(&Bs[kk][tx * 8]);
            *(float4*)(b + 4) = *(float4*)(&Bs[kk][tx * 8 + 4]);
#pragma unroll
            for (int i = 0; i < 8; ++i)
#pragma unroll
                for (int j = 0; j < 8; ++j)
                    acc[i][j] = fmaf(a[i], b[j], acc[i][j]);
        }
        __syncthreads();
    }
    for (int i = 0; i < 8; ++i) {
        float4* dst = (float4*)(&C[(size_t)(bm + ty * 8 + i) * Q + bn + tx * 8]);
        dst[0] = *(float4*)(&acc[i][0]);
        dst[1] = *(float4*)(&acc[i][4]);
    }
}

// C[m][n] = sum_k X[m][k] * Y[n][k]
__global__ __launch_bounds__(256)
void gemm_nt_kernel(const float* __restrict__ X, const float* __restrict__ Y,
                    float* __restrict__ C, int M, int N, int K)
{
    __shared__ float Xs[8][132];
    __shared__ float Ys[8][132];
    const int tid = threadIdx.x;
    const int bm = blockIdx.y * 128;
    const int bn = blockIdx.x * 128;
    const int row = tid >> 1;
    const int kq  = (tid & 1) << 2;
    const int tx = tid & 15, ty = tid >> 4;
    float acc[8][8] = {};
    for (int k0 = 0; k0 < K; k0 += 8) {
        float4 xv = *(const float4*)(&X[(size_t)(bm + row) * K + k0 + kq]);
        float4 yv = *(const float4*)(&Y[(size_t)(bn + row) * K + k0 + kq]);
        Xs[kq + 0][row] = xv.x; Xs[kq + 1][row] = xv.y;
        Xs[kq + 2][row] = xv.z; Xs[kq + 3][row] = xv.w;
        Ys[kq + 0][row] = yv.x; Ys[kq + 1][row] = yv.y;
        Ys[kq + 2][row] = yv.z; Ys[kq + 3][row] = yv.w;
        __syncthreads();
#pragma unroll
        for (int kk = 0; kk < 8; ++kk) {
            float a[8], b[8];
            *(float4*)(a)     = *(float4*)(&Xs[kk][ty * 8]);
            *(float4*)(a + 4) = *(float4*)(&Xs[kk][ty * 8 + 4]);
            *(float4*)(b)     = *(float4*)(&Ys[kk][tx * 8]);
            *(float4*)(b + 4) = *(float4*)(&Ys[kk][tx * 8 + 4]);
#pragma unroll
            for (int i = 0; i < 8; ++i)
#pragma unroll
                for (int j = 0; j < 8; ++j)
                    acc[i][j] = fmaf(a[i], b[j], acc[i][j]);
        }
        __syncthreads();
    }
    for (int i = 0; i < 8; ++i) {
        float4* dst = (float4*)(&C[(size_t)(bm + ty * 8 + i) * N + bn + tx * 8]);
        dst[0] = *(float4*)(&acc[i][0]);
        dst[1] = *(float4*)(&acc[i][4]);
    }
}

__global__ void sumsq_stage1(const float* __restrict__ S, double* __restrict__ partial, size_t n)
{
    size_t i = (size_t)blockIdx.x * 256 + threadIdx.x;
    size_t stride = (size_t)gridDim.x * 256;
    double s = 0.0;
    for (; i < n; i += stride) { double v = (double)S[i]; s += v * v; }
    for (int off = 32; off; off >>= 1) s += __shfl_down(s, off, 64);
    __shared__ double wsum[4];
    int lane = threadIdx.x & 63, wid = threadIdx.x >> 6;
    if (lane == 0) wsum[wid] = s;
    __syncthreads();
    if (threadIdx.x == 0) partial[blockIdx.x] = wsum[0] + wsum[1] + wsum[2] + wsum[3];
}

// partial dot product of two arrays (for Gram-trick Frobenius norm)
__global__ void dot_stage1(const float* __restrict__ a, const float* __restrict__ b,
                           double* __restrict__ partial, size_t n)
{
    size_t i = (size_t)blockIdx.x * 256 + threadIdx.x;
    size_t stride = (size_t)gridDim.x * 256;
    double s = 0.0;
    for (; i < n; i += stride) s += (double)a[i] * (double)b[i];
    for (int off = 32; off; off >>= 1) s += __shfl_down(s, off, 64);
    __shared__ double wsum[4];
    int lane = threadIdx.x & 63, wid = threadIdx.x >> 6;
    if (lane == 0) wsum[wid] = s;
    __syncthreads();
    if (threadIdx.x == 0) partial[blockIdx.x] = wsum[0] + wsum[1] + wsum[2] + wsum[3];
}

__global__ void sumsq_stage2(const double* __restrict__ partial, int nblocks, float* __restrict__ scale)
{
    double s = 0.0;
    for (int i = threadIdx.x; i < nblocks; i += 256) s += partial[i];
    for (int off = 32; off; off >>= 1) s += __shfl_down(s, off, 64);
    __shared__ double wsum[4];
    int lane = threadIdx.x & 63, wid = threadIdx.x >> 6;
    if (lane == 0) wsum[wid] = s;
    __syncthreads();
    if (threadIdx.x == 0) {
        double nrm = sqrt(wsum[0] + wsum[1] + wsum[2] + wsum[3]);
        if (nrm < 1e-12) nrm = 1e-12;
        *scale = (float)(10.0 / nrm);
    }
}

// in-place row softmax over 9216 cols (max-free: args bounded to [-10,10])
__global__ __launch_bounds__(256)
void softmax_rows_kernel(float* __restrict__ S, const float* __restrict__ scale_p)
{
    const int row = blockIdx.x;
    float* rp = S + (size_t)row * 9216;
    const float scale = *scale_p;
    float v[36];
    float sum = 0.f;
#pragma unroll
    for (int i = 0; i < 36; ++i) {
        v[i] = expf(rp[i * 256 + threadIdx.x] * scale);
        sum += v[i];
    }
    for (int off = 32; off; off >>= 1) sum += __shfl_xor(sum, off, 64);
    __shared__ float reds[4];
    int wid = threadIdx.x >> 6;
    if ((threadIdx.x & 63) == 0) reds[wid] = sum;
    __syncthreads();
    sum = reds[0] + reds[1] + reds[2] + reds[3];
    float inv = 1.f / sum;
#pragma unroll
    for (int i = 0; i < 36; ++i) rp[i * 256 + threadIdx.x] = v[i] * inv;
}

// --- Path C: striped fused kernels -----------------------------------------

// S-tile (K=1152) -> exp(scale*S) -> P-stripe + per-row partial sums
__global__ __launch_bounds__(256)
void sexp_kernel(const float* __restrict__ A, const float* __restrict__ B,
                 float* __restrict__ P, float* __restrict__ rsP,
                 const float* __restrict__ scale_p, int p0)
{
    __shared__ float As[8][128];
    __shared__ float Bs[8][128];
    const int tid = threadIdx.x;
    const int bm = p0 + blockIdx.y * 128;  // absolute p
    const int bn = blockIdx.x * 128;       // q
    const int lr = tid >> 5;
    const int lc = (tid & 31) << 2;
    const int tx = tid & 15, ty = tid >> 4;
    float acc[8][8] = {};
    for (int k0 = 0; k0 < 1152; k0 += 8) {
        *(float4*)(&As[lr][lc]) = *(const float4*)(&A[(size_t)(k0 + lr) * 9216 + bm + lc]);
        *(float4*)(&Bs[lr][lc]) = *(const float4*)(&B[(size_t)(k0 + lr) * 9216 + bn + lc]);
        __syncthreads();
#pragma unroll
        for (int kk = 0; kk < 8; ++kk) {
            float a[8], b[8];
            *(float4*)(a)     = *(float4*)(&As[kk][ty * 8]);
            *(float4*)(a + 4) = *(float4*)(&As[kk][ty * 8 + 4]);
            *(float4*)(b)     = *(float4*)(&Bs[kk][tx * 8]);
            *(float4*)(b + 4) = *(float4*)(&Bs[kk][tx * 8 + 4]);
#pragma unroll
            for (int i = 0; i < 8; ++i)
#pragma unroll
                for (int j = 0; j < 8; ++j)
                    acc[i][j] = fmaf(a[i], b[j], acc[i][j]);
        }
        __syncthreads();
    }
    const float scale = *scale_p;
    __shared__ float rbuf[128][17];
#pragma unroll
    for (int i = 0; i < 8; ++i) {
        float e[8];
        float s = 0.f;
#pragma unroll
        for (int j = 0; j < 8; ++j) { e[j] = expf(scale * acc[i][j]); s += e[j]; }
        rbuf[ty * 8 + i][tx] = s;
        float4* dst = (float4*)(&P[(size_t)(bm - p0 + ty * 8 + i) * 9216 + bn + tx * 8]);
        dst[0] = *(float4*)(&e[0]);
        dst[1] = *(float4*)(&e[4]);
    }
    __syncthreads();
    if (tid < 128) {
        float s = 0.f;
#pragma unroll
        for (int t = 0; t < 16; ++t) s += rbuf[tid][t];
        rsP[(size_t)(bm + tid) * 72 + blockIdx.x] = s;
    }
}

__global__ void rowsum_inv_kernel(const float* __restrict__ rsP, float* __restrict__ inv,
                                  int p0, int n)
{
    int i = blockIdx.x * 256 + threadIdx.x;
    if (i >= n) return;
    int p = p0 + i;
    float s = 0.f;
    for (int b = 0; b < 72; ++b) s += rsP[(size_t)p * 72 + b];
    inv[p] = 1.f / s;
}

// R[c][p0+pl] = inv[p0+pl] * sum_q bgp[c][q] * P[pl][q]; 64x128 tile, K=9216
__global__ __launch_bounds__(256)
void pv_kernel(const float* __restrict__ X, const float* __restrict__ Y,
               const float* __restrict__ inv, float* __restrict__ R, int p0)
{
    __shared__ float Xs[8][68];
    __shared__ float Ys[8][132];
    const int tid = threadIdx.x;
    const int bm = blockIdx.y * 64;    // c base
    const int bn = blockIdx.x * 128;   // pl base
    const int tx = tid & 15, ty = tid >> 4;
    const int row = tid >> 1, kq = (tid & 1) << 2;
    float acc[4][8] = {};
    for (int k0 = 0; k0 < 9216; k0 += 8) {
        if (tid < 128) {
            float4 xv = *(const float4*)(&X[(size_t)(bm + row) * 9216 + k0 + kq]);
            Xs[kq + 0][row] = xv.x; Xs[kq + 1][row] = xv.y;
            Xs[kq + 2][row] = xv.z; Xs[kq + 3][row] = xv.w;
        }
        float4 yv = *(const float4*)(&Y[(size_t)(bn + row) * 9216 + k0 + kq]);
        Ys[kq + 0][row] = yv.x; Ys[kq + 1][row] = yv.y;
        Ys[kq + 2][row] = yv.z; Ys[kq + 3][row] = yv.w;
        __syncthreads();
#pragma unroll
        for (int kk = 0; kk < 8; ++kk) {
            float a[4], b[8];
            *(float4*)(a)     = *(float4*)(&Xs[kk][ty * 4]);
            *(float4*)(b)     = *(float4*)(&Ys[kk][tx * 8]);
            *(float4*)(b + 4) = *(float4*)(&Ys[kk][tx * 8 + 4]);
#pragma unroll
            for (int i = 0; i < 4; ++i)
#pragma unroll
                for (int j = 0; j < 8; ++j)
                    acc[i][j] = fmaf(a[i], b[j], acc[i][j]);
        }
        __syncthreads();
    }
    float iv[8];
    *(float4*)(iv)     = *(const float4*)(&inv[p0 + bn + tx * 8]);
    *(float4*)(iv + 4) = *(const float4*)(&inv[p0 + bn + tx * 8 + 4]);
#pragma unroll
    for (int i = 0; i < 4; ++i) {
        float o[8];
#pragma unroll
        for (int j = 0; j < 8; ++j) o[j] = acc[i][j] * iv[j];
        float4* dst = (float4*)(&R[(size_t)(bm + ty * 4 + i) * 9216 + p0 + bn + tx * 8]);
        dst[0] = *(float4*)(&o[0]);
        dst[1] = *(float4*)(&o[4]);
    }
}

__global__ void fold_mask_up_kernel(const float* __restrict__ R,
                                    const float* __restrict__ mask,
                                    float* __restrict__ up)
{
    int idx = blockIdx.x * 256 + threadIdx.x; // 128*96*96
    if (idx >= 128 * 96 * 96) return;
    int x = idx % 96;
    int y = (idx / 96) % 96;
    int c = idx / (96 * 96);
    float s = 0.f;
#pragma unroll
    for (int dy = 0; dy < 3; ++dy) {
        int yy = y + 1 - dy;
        if (yy < 0 || yy >= 96) continue;
#pragma unroll
        for (int dx = 0; dx < 3; ++dx) {
            int xx = x + 1 - dx;
            if (xx < 0 || xx >= 96) continue;
            s += R[(size_t)(c * 9 + dy * 3 + dx) * 9216 + yy * 96 + xx];
        }
    }
    float m = mask[(size_t)(2 * y) * 192 + 2 * x];
    s *= m;
    size_t base = (size_t)c * 192 * 192;
    up[base + (size_t)(2 * y) * 192 + 2 * x]         = s;
    up[base + (size_t)(2 * y) * 192 + 2 * x + 1]     = s;
    up[base + (size_t)(2 * y + 1) * 192 + 2 * x]     = s;
    up[base + (size_t)(2 * y + 1) * 192 + 2 * x + 1] = s;
}

extern "C" void kernel_launch(void* const* d_in, const int* in_sizes, int n_in,
                              void* d_out, int out_size, void* d_ws, size_t ws_size,
                              hipStream_t stream)
{
    const float* x    = (const float*)d_in[0];
    const float* mask = (const float*)d_in[1];
    const float* w[8];
    const float* b[8];
    for (int i = 0; i < 8; ++i) {
        w[i] = (const float*)d_in[2 + 2 * i];
        b[i] = (const float*)d_in[3 + 2 * i];
    }
    float* ws = (float*)d_ws;
    dim3 blk(256);

    // ---- shared conv front-end (peak 132 MB) ----
    const size_t o_h1 = 0;
    const size_t o_h2 = 18874368;
    const size_t o_h3 = 23592960;
    const size_t o_h4 = 0;
    const size_t o_h5 = 4718592;
    const size_t o_h6 = 9437184;

    conv2d_kernel<5, 1, 1, 3><<<dim3(48, 48, 4), blk, 0, stream>>>(
        x, w[0], b[0], ws + o_h1, 3, 32, 768, 768, 768, 768, 2);
    conv2d_kernel<3, 2, 1, 8><<<dim3(24, 24, 4), blk, 0, stream>>>(
        ws + o_h1, w[1], b[1], ws + o_h2, 32, 32, 768, 768, 384, 384, 1);
    conv2d_kernel<3, 1, 1, 32><<<dim3(24, 24, 8), blk, 0, stream>>>(
        ws + o_h2, w[2], b[2], ws + o_h3, 32, 64, 384, 384, 384, 384, 1);
    conv2d_kernel<3, 2, 1, 8><<<dim3(12, 12, 16), blk, 0, stream>>>(
        ws + o_h3, w[3], b[3], ws + o_h4, 64, 128, 384, 384, 192, 192, 1);
    conv2d_kernel<3, 1, 1, 32><<<dim3(12, 12, 16), blk, 0, stream>>>(
        ws + o_h4, w[4], b[4], ws + o_h5, 128, 128, 192, 192, 192, 192, 1);
    conv2d_kernel<3, 1, 0, 32><<<dim3(12, 12, 16), blk, 0, stream>>>(
        ws + o_h5, w[5], b[5], ws + o_h6, 128, 128, 192, 192, 192, 192, 1);

    const size_t o_fg  = 14155776;
    const size_t o_bg  = 15335424;
    const size_t o_fgp = 16515072;
    const size_t o_bgp = 27131904;

    downsample_mask_kernel<<<dim3(4608), blk, 0, stream>>>(ws + o_h6, mask, ws + o_fg, ws + o_bg);
    patches_kernel<<<dim3(41472), blk, 0, stream>>>(ws + o_fg, ws + o_fgp);
    patches_kernel<<<dim3(41472), blk, 0, stream>>>(ws + o_bg, ws + o_bgp);

    const size_t o_up = 0;
    const size_t o_h7 = 4718592;

    if (ws_size >= (size_t)491000000) {
        // ---- Path A: materialize S fp32 (peak 491 MB) ----
        const size_t o_S     = 37748736;
        const size_t o_red   = 122683392; // 2048 doubles
        const size_t o_scale = o_red + 4096;
        const size_t o_R     = 14155776;  // reuses fg/fgp region

        gemm_tn_kernel<<<dim3(72, 72), blk, 0, stream>>>(ws + o_fgp, ws + o_bgp, ws + o_S, 9216, 9216, 1152);
        sumsq_stage1<<<dim3(2048), blk, 0, stream>>>(ws + o_S, (double*)(ws + o_red), (size_t)9216 * 9216);
        sumsq_stage2<<<dim3(1), blk, 0, stream>>>((const double*)(ws + o_red), 2048, ws + o_scale);
        softmax_rows_kernel<<<dim3(9216), blk, 0, stream>>>(ws + o_S, ws + o_scale);
        gemm_nt_kernel<<<dim3(72, 9), blk, 0, stream>>>(ws + o_bgp, ws + o_S, ws + o_R, 1152, 9216, 9216);
        fold_mask_up_kernel<<<dim3(4608), blk, 0, stream>>>(ws + o_R, mask, ws + o_up);
    } else {
        // ---- Path C: no S (peak 207 MB) ----
        const size_t o_GF    = 37748736;  // 1152x1152
        const size_t o_GB    = 39075840;
        const size_t o_red   = 40402944;  // 2048 doubles
        const size_t o_scale = 40407040;
        const size_t o_rsP   = 40407296;  // 9216 x 72
        const size_t o_inv   = 41070848;  // 9216
        const size_t o_P     = 0;         // 1536 x 9216 stripe (h4..h6 region, dead)
        const size_t o_R     = 41080064;  // 1152 x 9216

        // scale = 10 / ||S||_F via tr((F F^T)(B B^T))
        gemm_nt_kernel<<<dim3(9, 9), blk, 0, stream>>>(ws + o_fgp, ws + o_fgp, ws + o_GF, 1152, 1152, 9216);
        gemm_nt_kernel<<<dim3(9, 9), blk, 0, stream>>>(ws + o_bgp, ws + o_bgp, ws + o_GB, 1152, 1152, 9216);
        dot_stage1<<<dim3(512), blk, 0, stream>>>(ws + o_GF, ws + o_GB, (double*)(ws + o_red), (size_t)1152 * 1152);
        sumsq_stage2<<<dim3(1), blk, 0, stream>>>((const double*)(ws + o_red), 512, ws + o_scale);

        for (int s = 0; s < 6; ++s) {
            int p0 = s * 1536;
            sexp_kernel<<<dim3(72, 12), blk, 0, stream>>>(
                ws + o_fgp, ws + o_bgp, ws + o_P, ws + o_rsP, ws + o_scale, p0);
            rowsum_inv_kernel<<<dim3(6), blk, 0, stream>>>(ws + o_rsP, ws + o_inv, p0, 1536);
            pv_kernel<<<dim3(12, 18), blk, 0, stream>>>(
                ws + o_bgp, ws + o_P, ws + o_inv, ws + o_R, p0);
        }
        fold_mask_up_kernel<<<dim3(4608), blk, 0, stream>>>(ws + o_R, mask, ws + o_up);
    }

    conv2d_kernel<3, 1, 1, 32><<<dim3(12, 12, 16), blk, 0, stream>>>(
        ws + o_up, w[6], b[6], ws + o_h7, 128, 128, 192, 192, 192, 192, 1);
    conv2d_kernel<3, 1, 1, 32><<<dim3(12, 12, 16), blk, 0, stream>>>(
        ws + o_h7, w[7], b[7], (float*)d_out, 128, 128, 192, 192, 192, 192, 1);
}

// Round 3
// 3455.542 us; speedup vs baseline: 3.8594x; 3.8594x over previous
//
#include <hip/hip_runtime.h>
#include <math.h>

// ---------------------------------------------------------------------------
// Round 2: bf16-MFMA attention GEMMs (S-exp, PV, Gram-norm), fp32 convs kept.
// Workspace (bytes, peak 180.6 MB < 207 MB known-safe):
//  frontend: h1@0 h2@75,497,472 h3@94,371,840 | h4@0 h5@18,874,368 h6@37,748,736
//  fgpT@56,623,104 bgpT@77,856,768 fgpK@99,090,432 bgpK@120,324,096 (bf16 [9216][1152]/[1152][9216])
//  P@141,557,760 (bf16 9216x1536 stripe) GF@169,869,312 GB@175,177,728
//  red@180,486,144 scale@180,490,240 rs@180,490,496 inv@180,527,360
//  R2@0 (fp32 [1152][9216], after h6 dead) up@56,623,104 h7@75,497,472
// ---------------------------------------------------------------------------

typedef unsigned short u16;
typedef short short8v __attribute__((ext_vector_type(8)));
typedef float f32x4 __attribute__((ext_vector_type(4)));

__device__ __forceinline__ u16 f2bf(float f) {
    unsigned u = __float_as_uint(f);
    return (u16)((u + 0x7FFF + ((u >> 16) & 1)) >> 16);
}
__device__ __forceinline__ float bf2f(u16 h) {
    return __uint_as_float(((unsigned)h) << 16);
}

#define TILE 16

// ---------------- convs (unchanged from round 1) ----------------------------
template<int KS, int STRIDE, int ACT, int CHUNK>
__global__ __launch_bounds__(256)
void conv2d_kernel(const float* __restrict__ in, const float* __restrict__ wgt,
                   const float* __restrict__ bias, float* __restrict__ out,
                   int Cin, int Cout, int H, int W, int Ho, int Wo, int pad)
{
    constexpr int TIN = (TILE - 1) * STRIDE + KS;
    constexpr int OCPT = 8;
    __shared__ float sIn[CHUNK][TIN][TIN + 1];

    const int tx = threadIdx.x & 15;
    const int ty = threadIdx.x >> 4;
    const int ox0 = blockIdx.x * TILE;
    const int oy0 = blockIdx.y * TILE;
    const int oc0 = blockIdx.z * OCPT;

    float acc[OCPT];
#pragma unroll
    for (int o = 0; o < OCPT; ++o) acc[o] = 0.f;

    const int ksq = KS * KS;
    for (int c0 = 0; c0 < Cin; c0 += CHUNK) {
        for (int idx = threadIdx.x; idx < CHUNK * TIN * TIN; idx += 256) {
            int c   = idx / (TIN * TIN);
            int rem = idx - c * (TIN * TIN);
            int y   = rem / TIN;
            int x   = rem - y * TIN;
            int gy = oy0 * STRIDE - pad + y;
            int gx = ox0 * STRIDE - pad + x;
            gy = gy < 0 ? -gy : (gy >= H ? 2 * H - 2 - gy : gy);
            gx = gx < 0 ? -gx : (gx >= W ? 2 * W - 2 - gx : gx);
            sIn[c][y][x] = in[(size_t)(c0 + c) * H * W + (size_t)gy * W + gx];
        }
        __syncthreads();
#pragma unroll 2
        for (int c = 0; c < CHUNK; ++c) {
            const float* wp = wgt + ((size_t)oc0 * Cin + (size_t)(c0 + c)) * ksq;
#pragma unroll
            for (int ky = 0; ky < KS; ++ky) {
#pragma unroll
                for (int kx = 0; kx < KS; ++kx) {
                    float v = sIn[c][ty * STRIDE + ky][tx * STRIDE + kx];
#pragma unroll
                    for (int o = 0; o < OCPT; ++o)
                        acc[o] = fmaf(v, wp[(size_t)o * Cin * ksq + ky * KS + kx], acc[o]);
                }
            }
        }
        __syncthreads();
    }
    const int oy = oy0 + ty, ox = ox0 + tx;
#pragma unroll
    for (int o = 0; o < OCPT; ++o) {
        float v = acc[o] + bias[oc0 + o];
        if (ACT == 0) v = v > 0.f ? v : 0.f;
        else          v = v > 0.f ? v : expm1f(v);
        out[(size_t)(oc0 + o) * Ho * Wo + (size_t)oy * Wo + ox] = v;
    }
}

// ---------------- patch builders (bf16, 4 layouts) --------------------------
// fg(c,y,x) = h6[c][2y][2x] * mask[2y][2x]; bg without mask; zero-pad outside.
__global__ void build_patches_T(const float* __restrict__ h6, const float* __restrict__ mask,
                                u16* __restrict__ fgpT, u16* __restrict__ bgpT)
{
    int idx = blockIdx.x * 256 + threadIdx.x;   // p*1152 + k
    if (idx >= 9216 * 1152) return;
    int p = idx / 1152, k = idx - p * 1152;
    int y = p / 96, x = p - y * 96;
    int c = k / 9, t = k - c * 9;
    int dy = t / 3, dx = t - dy * 3;
    int sy = y + dy - 1, sx = x + dx - 1;
    float v = 0.f, vm = 0.f;
    if (sy >= 0 && sy < 96 && sx >= 0 && sx < 96) {
        v  = h6[(size_t)c * 36864 + (size_t)(2 * sy) * 192 + 2 * sx];
        vm = v * mask[(size_t)(2 * sy) * 192 + 2 * sx];
    }
    bgpT[idx] = f2bf(v);
    fgpT[idx] = f2bf(vm);
}

__global__ void build_patches_K(const float* __restrict__ h6, const float* __restrict__ mask,
                                u16* __restrict__ fgpK, u16* __restrict__ bgpK)
{
    int idx = blockIdx.x * 256 + threadIdx.x;   // k*9216 + q
    if (idx >= 9216 * 1152) return;
    int k = idx / 9216, q = idx - k * 9216;
    int y = q / 96, x = q - y * 96;
    int c = k / 9, t = k - c * 9;
    int dy = t / 3, dx = t - dy * 3;
    int sy = y + dy - 1, sx = x + dx - 1;
    float v = 0.f, vm = 0.f;
    if (sy >= 0 && sy < 96 && sx >= 0 && sx < 96) {
        v  = h6[(size_t)c * 36864 + (size_t)(2 * sy) * 192 + 2 * sx];
        vm = v * mask[(size_t)(2 * sy) * 192 + 2 * sx];
    }
    bgpK[idx] = f2bf(v);
    fgpK[idx] = f2bf(vm);
}

// ---------------- unified bf16 NT MFMA GEMM --------------------------------
// D[m][n] = sum_k A[m][k] * B[n][k]; 128x128 tile, 4 waves (2x2), BK=64.
// EPI: 0 = fp32 store (Gram), 1 = exp(scale*v)->bf16 store (S), 2 = fp32 += (PV)
template<int EPI>
__global__ __launch_bounds__(256)
void mfma_nt_kernel(const u16* __restrict__ A, const u16* __restrict__ B,
                    int lda, int ldb, int K,
                    float* __restrict__ outF, u16* __restrict__ outH, int ldo,
                    const float* __restrict__ scale_p)
{
    __shared__ u16 As[128 * 64];
    __shared__ u16 Bs[128 * 64];
    const int tid  = threadIdx.x;
    const int wid  = tid >> 6;
    const int lane = tid & 63;
    const int wm = (wid >> 1) * 64;
    const int wn = (wid & 1) * 64;
    const size_t bm = (size_t)blockIdx.y * 128;
    const size_t bn = (size_t)blockIdx.x * 128;

    f32x4 acc[4][4];
#pragma unroll
    for (int i = 0; i < 4; ++i)
#pragma unroll
        for (int j = 0; j < 4; ++j)
            acc[i][j] = (f32x4){0.f, 0.f, 0.f, 0.f};

    const int srow = tid >> 3;          // 0..31
    const int skb  = (tid & 7) * 16;    // byte 0..112 within 128B row

    for (int k0 = 0; k0 < K; k0 += 64) {
        short8v ra[4], rb[4];
#pragma unroll
        for (int i = 0; i < 4; ++i) {
            int m = srow + i * 32;
            ra[i] = *(const short8v*)((const char*)A + ((size_t)(bm + m) * lda + k0) * 2 + skb);
            rb[i] = *(const short8v*)((const char*)B + ((size_t)(bn + m) * ldb + k0) * 2 + skb);
        }
        __syncthreads();   // prev compute done before overwriting LDS
#pragma unroll
        for (int i = 0; i < 4; ++i) {
            int m = srow + i * 32;
            int kbs = skb ^ ((m & 7) << 4);
            *(short8v*)((char*)As + m * 128 + kbs) = ra[i];
            *(short8v*)((char*)Bs + m * 128 + kbs) = rb[i];
        }
        __syncthreads();
#pragma unroll
        for (int ks = 0; ks < 2; ++ks) {
            short8v a[4], b[4];
#pragma unroll
            for (int f = 0; f < 4; ++f) {
                int ma = wm + f * 16 + (lane & 15);
                int kba = (ks * 64 + ((lane >> 4) * 16)) ^ ((ma & 7) << 4);
                a[f] = *(const short8v*)((const char*)As + ma * 128 + kba);
                int nb = wn + f * 16 + (lane & 15);
                int kbb = (ks * 64 + ((lane >> 4) * 16)) ^ ((nb & 7) << 4);
                b[f] = *(const short8v*)((const char*)Bs + nb * 128 + kbb);
            }
#pragma unroll
            for (int fm = 0; fm < 4; ++fm)
#pragma unroll
                for (int fn = 0; fn < 4; ++fn)
                    acc[fm][fn] = __builtin_amdgcn_mfma_f32_16x16x32_bf16(
                        a[fm], b[fn], acc[fm][fn], 0, 0, 0);
        }
    }

    const float scale = (EPI == 1) ? *scale_p : 0.f;
#pragma unroll
    for (int fm = 0; fm < 4; ++fm) {
#pragma unroll
        for (int fn = 0; fn < 4; ++fn) {
#pragma unroll
            for (int i = 0; i < 4; ++i) {
                int r = wm + fm * 16 + ((lane >> 4) * 4) + i;
                int c = wn + fn * 16 + (lane & 15);
                float v = acc[fm][fn][i];
                if (EPI == 0) {
                    outF[(bm + r) * (size_t)ldo + bn + c] = v;
                } else if (EPI == 1) {
                    outH[(bm + r) * (size_t)ldo + bn + c] = f2bf(__expf(scale * v));
                } else {
                    outF[(bm + r) * (size_t)ldo + bn + c] += v;
                }
            }
        }
    }
}

// ---------------- norm reductions ------------------------------------------
__global__ void dot_stage1(const float* __restrict__ a, const float* __restrict__ b,
                           double* __restrict__ partial, size_t n)
{
    size_t i = (size_t)blockIdx.x * 256 + threadIdx.x;
    size_t stride = (size_t)gridDim.x * 256;
    double s = 0.0;
    for (; i < n; i += stride) s += (double)a[i] * (double)b[i];
    for (int off = 32; off; off >>= 1) s += __shfl_down(s, off, 64);
    __shared__ double wsum[4];
    int lane = threadIdx.x & 63, wid = threadIdx.x >> 6;
    if (lane == 0) wsum[wid] = s;
    __syncthreads();
    if (threadIdx.x == 0) partial[blockIdx.x] = wsum[0] + wsum[1] + wsum[2] + wsum[3];
}

__global__ void sumsq_stage2(const double* __restrict__ partial, int nblocks, float* __restrict__ scale)
{
    double s = 0.0;
    for (int i = threadIdx.x; i < nblocks; i += 256) s += partial[i];
    for (int off = 32; off; off >>= 1) s += __shfl_down(s, off, 64);
    __shared__ double wsum[4];
    int lane = threadIdx.x & 63, wid = threadIdx.x >> 6;
    if (lane == 0) wsum[wid] = s;
    __syncthreads();
    if (threadIdx.x == 0) {
        double nrm = sqrt(wsum[0] + wsum[1] + wsum[2] + wsum[3]);
        if (nrm < 1e-12) nrm = 1e-12;
        *scale = (float)(10.0 / nrm);
    }
}

// rs[row] += sum over 1536 bf16 of P stripe; 4 waves/block, 1 row/wave
__global__ void rowsum_accum(const u16* __restrict__ P, float* __restrict__ rs)
{
    int wid = threadIdx.x >> 6, lane = threadIdx.x & 63;
    int row = blockIdx.x * 4 + wid;   // grid 2304
    const u16* rp = P + (size_t)row * 1536;
    float s = 0.f;
#pragma unroll
    for (int j = 0; j < 3; ++j) {
        short8v v = *(const short8v*)(rp + j * 512 + lane * 8);
#pragma unroll
        for (int e = 0; e < 8; ++e) s += bf2f((u16)v[e]);
    }
    for (int off = 32; off; off >>= 1) s += __shfl_down(s, off, 64);
    if (lane == 0) rs[row] += s;
}

__global__ void inv_kernel(const float* __restrict__ rs, float* __restrict__ inv)
{
    int i = blockIdx.x * 256 + threadIdx.x;
    if (i < 9216) inv[i] = 1.f / rs[i];
}

// ---------------- fold + mask + upsample ------------------------------------
// R2 layout [ck=1152][p=9216], normalized by inv[p] here.
__global__ void fold_mask_up_kernel(const float* __restrict__ R2,
                                    const float* __restrict__ inv,
                                    const float* __restrict__ mask,
                                    float* __restrict__ up)
{
    int idx = blockIdx.x * 256 + threadIdx.x; // 128*96*96
    if (idx >= 128 * 96 * 96) return;
    int x = idx % 96;
    int y = (idx / 96) % 96;
    int c = idx / (96 * 96);
    float s = 0.f;
#pragma unroll
    for (int dy = 0; dy < 3; ++dy) {
        int yy = y + 1 - dy;
        if (yy < 0 || yy >= 96) continue;
#pragma unroll
        for (int dx = 0; dx < 3; ++dx) {
            int xx = x + 1 - dx;
            if (xx < 0 || xx >= 96) continue;
            int pp = yy * 96 + xx;
            s += R2[(size_t)(c * 9 + dy * 3 + dx) * 9216 + pp] * inv[pp];
        }
    }
    s *= mask[(size_t)(2 * y) * 192 + 2 * x];
    size_t base = (size_t)c * 192 * 192;
    up[base + (size_t)(2 * y) * 192 + 2 * x]         = s;
    up[base + (size_t)(2 * y) * 192 + 2 * x + 1]     = s;
    up[base + (size_t)(2 * y + 1) * 192 + 2 * x]     = s;
    up[base + (size_t)(2 * y + 1) * 192 + 2 * x + 1] = s;
}

// ---------------------------------------------------------------------------
extern "C" void kernel_launch(void* const* d_in, const int* in_sizes, int n_in,
                              void* d_out, int out_size, void* d_ws, size_t ws_size,
                              hipStream_t stream)
{
    const float* x    = (const float*)d_in[0];
    const float* mask = (const float*)d_in[1];
    const float* w[8];
    const float* b[8];
    for (int i = 0; i < 8; ++i) {
        w[i] = (const float*)d_in[2 + 2 * i];
        b[i] = (const float*)d_in[3 + 2 * i];
    }
    char* ws = (char*)d_ws;
    dim3 blk(256);

    // byte offsets
    const size_t F_H1   = 0;
    const size_t F_H2   = 75497472;
    const size_t F_H3   = 94371840;
    const size_t F_H4   = 0;
    const size_t F_H5   = 18874368;
    const size_t F_H6   = 37748736;
    const size_t U_FGPT = 56623104;
    const size_t U_BGPT = 77856768;
    const size_t U_FGPK = 99090432;
    const size_t U_BGPK = 120324096;
    const size_t U_P    = 141557760;
    const size_t F_GF   = 169869312;
    const size_t F_GB   = 175177728;
    const size_t D_RED  = 180486144;
    const size_t F_SCALE= 180490240;
    const size_t F_RS   = 180490496;
    const size_t F_INV  = 180527360;
    const size_t F_R2   = 0;
    const size_t F_UP   = 56623104;
    const size_t F_H7   = 75497472;

    float* h1 = (float*)(ws + F_H1);
    float* h2 = (float*)(ws + F_H2);
    float* h3 = (float*)(ws + F_H3);
    float* h4 = (float*)(ws + F_H4);
    float* h5 = (float*)(ws + F_H5);
    float* h6 = (float*)(ws + F_H6);
    u16* fgpT = (u16*)(ws + U_FGPT);
    u16* bgpT = (u16*)(ws + U_BGPT);
    u16* fgpK = (u16*)(ws + U_FGPK);
    u16* bgpK = (u16*)(ws + U_BGPK);
    u16* P    = (u16*)(ws + U_P);
    float* GF = (float*)(ws + F_GF);
    float* GB = (float*)(ws + F_GB);
    double* red = (double*)(ws + D_RED);
    float* scale = (float*)(ws + F_SCALE);
    float* rs  = (float*)(ws + F_RS);
    float* inv = (float*)(ws + F_INV);
    float* R2  = (float*)(ws + F_R2);
    float* up  = (float*)(ws + F_UP);
    float* h7  = (float*)(ws + F_H7);

    // ---- conv front-end ----
    conv2d_kernel<5, 1, 1, 3><<<dim3(48, 48, 4), blk, 0, stream>>>(
        x, w[0], b[0], h1, 3, 32, 768, 768, 768, 768, 2);
    conv2d_kernel<3, 2, 1, 8><<<dim3(24, 24, 4), blk, 0, stream>>>(
        h1, w[1], b[1], h2, 32, 32, 768, 768, 384, 384, 1);
    conv2d_kernel<3, 1, 1, 32><<<dim3(24, 24, 8), blk, 0, stream>>>(
        h2, w[2], b[2], h3, 32, 64, 384, 384, 384, 384, 1);
    conv2d_kernel<3, 2, 1, 8><<<dim3(12, 12, 16), blk, 0, stream>>>(
        h3, w[3], b[3], h4, 64, 128, 384, 384, 192, 192, 1);
    conv2d_kernel<3, 1, 1, 32><<<dim3(12, 12, 16), blk, 0, stream>>>(
        h4, w[4], b[4], h5, 128, 128, 192, 192, 192, 192, 1);
    conv2d_kernel<3, 1, 0, 32><<<dim3(12, 12, 16), blk, 0, stream>>>(
        h5, w[5], b[5], h6, 128, 128, 192, 192, 192, 192, 1);

    // ---- patch matrices (4 bf16 layouts) ----
    build_patches_T<<<dim3(41472), blk, 0, stream>>>(h6, mask, fgpT, bgpT);
    build_patches_K<<<dim3(41472), blk, 0, stream>>>(h6, mask, fgpK, bgpK);

    // ---- norm scale via Gram trick: ||S||^2 = tr((F F^T)(B B^T)) ----
    mfma_nt_kernel<0><<<dim3(9, 9), blk, 0, stream>>>(
        fgpK, fgpK, 9216, 9216, 9216, GF, nullptr, 1152, nullptr);
    mfma_nt_kernel<0><<<dim3(9, 9), blk, 0, stream>>>(
        bgpK, bgpK, 9216, 9216, 9216, GB, nullptr, 1152, nullptr);
    dot_stage1<<<dim3(512), blk, 0, stream>>>(GF, GB, red, (size_t)1152 * 1152);
    sumsq_stage2<<<dim3(1), blk, 0, stream>>>(red, 512, scale);

    // ---- zero accumulators (h6 dead from here) ----
    hipMemsetAsync(R2, 0, (size_t)1152 * 9216 * 4, stream);
    hipMemsetAsync(rs, 0, 9216 * 4, stream);

    // ---- 6 q-stripes: S-exp (P stripe), rowsum accumulate, PV accumulate ----
    for (int s = 0; s < 6; ++s) {
        size_t qs = (size_t)s * 1536;
        mfma_nt_kernel<1><<<dim3(12, 72), blk, 0, stream>>>(
            fgpT, bgpT + qs * 1152, 1152, 1152, 1152, nullptr, P, 1536, scale);
        rowsum_accum<<<dim3(2304), blk, 0, stream>>>(P, rs);
        mfma_nt_kernel<2><<<dim3(72, 9), blk, 0, stream>>>(
            bgpK + qs, P, 9216, 1536, 1536, R2, nullptr, 9216, nullptr);
    }
    inv_kernel<<<dim3(36), blk, 0, stream>>>(rs, inv);
    fold_mask_up_kernel<<<dim3(4608), blk, 0, stream>>>(R2, inv, mask, up);

    // ---- back-end convs ----
    conv2d_kernel<3, 1, 1, 32><<<dim3(12, 12, 16), blk, 0, stream>>>(
        up, w[6], b[6], h7, 128, 128, 192, 192, 192, 192, 1);
    conv2d_kernel<3, 1, 1, 32><<<dim3(12, 12, 16), blk, 0, stream>>>(
        h7, w[7], b[7], (float*)d_out, 128, 128, 192, 192, 192, 192, 1);
}

// Round 4
// 1647.169 us; speedup vs baseline: 8.0966x; 2.0979x over previous
//
#include <hip/hip_runtime.h>
#include <math.h>

// ---------------------------------------------------------------------------
// Round 3: MFMA implicit-GEMM convs (conv3..8, channels-last bf16) + bf16
// attention. conv1/conv2 remain direct fp32 (conv2 emits ch-last bf16).
// Workspace peak 172.5 MB (< 180.56 MB proven safe in round 2).
// ---------------------------------------------------------------------------

typedef unsigned short u16;
typedef short short8v __attribute__((ext_vector_type(8)));
typedef float f32x4 __attribute__((ext_vector_type(4)));

__device__ __forceinline__ u16 f2bf(float f) {
    unsigned u = __float_as_uint(f);
    return (u16)((u + 0x7FFF + ((u >> 16) & 1)) >> 16);
}
__device__ __forceinline__ float bf2f(u16 h) {
    return __uint_as_float(((unsigned)h) << 16);
}

#define TILE 16

// ---------------- direct conv (conv1, conv2) --------------------------------
// OUTCL: 0 = planar fp32 out, 1 = channels-last bf16 out
template<int KS, int STRIDE, int ACT, int CHUNK, int OUTCL>
__global__ __launch_bounds__(256)
void conv2d_kernel(const float* __restrict__ in, const float* __restrict__ wgt,
                   const float* __restrict__ bias, void* __restrict__ out,
                   int Cin, int Cout, int H, int W, int Ho, int Wo, int pad)
{
    constexpr int TIN = (TILE - 1) * STRIDE + KS;
    constexpr int OCPT = 8;
    __shared__ float sIn[CHUNK][TIN][TIN + 1];

    const int tx = threadIdx.x & 15;
    const int ty = threadIdx.x >> 4;
    const int ox0 = blockIdx.x * TILE;
    const int oy0 = blockIdx.y * TILE;
    const int oc0 = blockIdx.z * OCPT;

    float acc[OCPT];
#pragma unroll
    for (int o = 0; o < OCPT; ++o) acc[o] = 0.f;

    const int ksq = KS * KS;
    for (int c0 = 0; c0 < Cin; c0 += CHUNK) {
        for (int idx = threadIdx.x; idx < CHUNK * TIN * TIN; idx += 256) {
            int c   = idx / (TIN * TIN);
            int rem = idx - c * (TIN * TIN);
            int y   = rem / TIN;
            int x   = rem - y * TIN;
            int gy = oy0 * STRIDE - pad + y;
            int gx = ox0 * STRIDE - pad + x;
            gy = gy < 0 ? -gy : (gy >= H ? 2 * H - 2 - gy : gy);
            gx = gx < 0 ? -gx : (gx >= W ? 2 * W - 2 - gx : gx);
            sIn[c][y][x] = in[(size_t)(c0 + c) * H * W + (size_t)gy * W + gx];
        }
        __syncthreads();
#pragma unroll 2
        for (int c = 0; c < CHUNK; ++c) {
            const float* wp = wgt + ((size_t)oc0 * Cin + (size_t)(c0 + c)) * ksq;
#pragma unroll
            for (int ky = 0; ky < KS; ++ky) {
#pragma unroll
                for (int kx = 0; kx < KS; ++kx) {
                    float v = sIn[c][ty * STRIDE + ky][tx * STRIDE + kx];
#pragma unroll
                    for (int o = 0; o < OCPT; ++o)
                        acc[o] = fmaf(v, wp[(size_t)o * Cin * ksq + ky * KS + kx], acc[o]);
                }
            }
        }
        __syncthreads();
    }
    const int oy = oy0 + ty, ox = ox0 + tx;
#pragma unroll
    for (int o = 0; o < OCPT; ++o) {
        float v = acc[o] + bias[oc0 + o];
        if (ACT == 0) v = v > 0.f ? v : 0.f;
        else          v = v > 0.f ? v : expm1f(v);
        if (OUTCL)
            ((u16*)out)[((size_t)oy * Wo + ox) * Cout + oc0 + o] = f2bf(v);
        else
            ((float*)out)[(size_t)(oc0 + o) * Ho * Wo + (size_t)oy * Wo + ox] = v;
    }
}

// ---------------- weight prepack: [oc][ic][3][3] f32 -> [oc][tap][ic] bf16 --
__global__ void pack_w_kernel(const float* __restrict__ w, u16* __restrict__ wp,
                              int OC, int IC)
{
    int idx = blockIdx.x * 256 + threadIdx.x;
    if (idx >= OC * 9 * IC) return;
    int oc = idx / (9 * IC);
    int r  = idx - oc * 9 * IC;
    int tap = r / IC;
    int ic  = r - tap * IC;
    wp[idx] = f2bf(w[((size_t)oc * IC + ic) * 9 + tap]);
}

// ---------------- MFMA implicit-GEMM conv (3x3, reflect pad 1) --------------
// channels-last bf16 in [H][W][IC]; out [Ho][Wo][OC] bf16 (or fp32 if OUTF32).
// M-tile = 128 spatial (8 rows x 16 cols), N-tile = NWN*FN*16 = OC.
// ICC = channels staged per LDS pass (ICC == IC when it fits under 64KB).
template<int FM, int FN, int NWM, int NWN, int S, int IC, int ICC, int ACT, int OUTF32>
__global__ __launch_bounds__(256)
void mfma_conv_kernel(const u16* __restrict__ in, const u16* __restrict__ wgtP,
                      const float* __restrict__ bias, void* __restrict__ out,
                      int H, int W, int Ho, int Wo, int OC)
{
    constexpr int TY = 7 * S + 3;
    constexpr int TX = 15 * S + 3;
    constexpr int NSLOT = ICC / 8;
    constexpr int SWMSK = NSLOT - 1;
    constexpr int KTOT = 9 * IC;
    __shared__ __align__(16) u16 sIn[TY * TX * ICC];

    const int tid  = threadIdx.x;
    const int lane = tid & 63;
    const int wid  = tid >> 6;
    const int wmi  = wid / NWN;
    const int wni  = wid % NWN;
    const int lm   = lane & 15;
    const int lk   = lane >> 4;

    f32x4 acc[FM][FN];
#pragma unroll
    for (int i = 0; i < FM; ++i)
#pragma unroll
        for (int j = 0; j < FN; ++j) acc[i][j] = (f32x4){0.f, 0.f, 0.f, 0.f};

    const int iy0 = blockIdx.y * 8 * S - 1;
    const int ix0 = blockIdx.x * 16 * S - 1;

    for (int c0 = 0; c0 < IC; c0 += ICC) {
        if (c0) __syncthreads();
        // stage halo tile (reflect pad), swizzled slot = sl ^ (xt & SWMSK)
        for (int u = tid; u < TY * TX * NSLOT; u += 256) {
            int yt = u / (TX * NSLOT);
            int r  = u - yt * (TX * NSLOT);
            int xt = r / NSLOT;
            int sl = r - xt * NSLOT;
            int gy = iy0 + yt; gy = gy < 0 ? -gy : (gy >= H ? 2 * H - 2 - gy : gy);
            int gx = ix0 + xt; gx = gx < 0 ? -gx : (gx >= W ? 2 * W - 2 - gx : gx);
            *(short8v*)((char*)sIn + (size_t)((yt * TX + xt) * NSLOT + (sl ^ (xt & SWMSK))) * 16) =
                *(const short8v*)(in + ((size_t)gy * W + gx) * IC + c0 + sl * 8);
        }
        __syncthreads();
#pragma unroll
        for (int tap = 0; tap < 9; ++tap) {
            const int dy = tap / 3, dx = tap % 3;
#pragma unroll
            for (int icw = 0; icw < ICC / 32; ++icw) {
                short8v a[FM], b[FN];
#pragma unroll
                for (int fm = 0; fm < FM; ++fm) {
                    int yt = (wmi * FM + fm) * S + dy;
                    int xt = lm * S + dx;
                    a[fm] = *(const short8v*)((const char*)sIn +
                        (size_t)((yt * TX + xt) * NSLOT + ((icw * 4 + lk) ^ (xt & SWMSK))) * 16);
                }
#pragma unroll
                for (int fn = 0; fn < FN; ++fn) {
                    int n = wni * FN * 16 + fn * 16 + lm;
                    b[fn] = *(const short8v*)(wgtP + (size_t)n * KTOT + tap * IC + c0 + icw * 32 + lk * 8);
                }
#pragma unroll
                for (int fm = 0; fm < FM; ++fm)
#pragma unroll
                    for (int fn = 0; fn < FN; ++fn)
                        acc[fm][fn] = __builtin_amdgcn_mfma_f32_16x16x32_bf16(
                            a[fm], b[fn], acc[fm][fn], 0, 0, 0);
            }
        }
    }

#pragma unroll
    for (int fm = 0; fm < FM; ++fm) {
        int y = blockIdx.y * 8 + wmi * FM + fm;
#pragma unroll
        for (int fn = 0; fn < FN; ++fn) {
            int oc = wni * FN * 16 + fn * 16 + lm;
            float bv = bias[oc];
#pragma unroll
            for (int i = 0; i < 4; ++i) {
                int x = blockIdx.x * 16 + lk * 4 + i;
                float v = acc[fm][fn][i] + bv;
                if (ACT == 0) v = v > 0.f ? v : 0.f;
                else          v = v > 0.f ? v : expm1f(v);
                size_t o = ((size_t)y * Wo + x) * OC + oc;
                if (OUTF32) ((float*)out)[o] = v;
                else        ((u16*)out)[o]   = f2bf(v);
            }
        }
    }
}

// ---------------- layout transposes -----------------------------------------
// planar f32 [128][36864] -> channels-last bf16 [36864][128]
__global__ __launch_bounds__(256)
void p2cl_kernel(const float* __restrict__ in, u16* __restrict__ out)
{
    __shared__ float t[32][130];
    const int tid = threadIdx.x;
    const int p0 = blockIdx.x * 32;
#pragma unroll
    for (int j = 0; j < 16; ++j) {
        int c = j * 8 + (tid >> 5);
        int px = tid & 31;
        t[px][c] = in[(size_t)c * 36864 + p0 + px];
    }
    __syncthreads();
#pragma unroll
    for (int j = 0; j < 16; ++j) {
        int idx = j * 256 + tid;
        int px = idx >> 7, c = idx & 127;
        out[(size_t)(p0 + px) * 128 + c] = f2bf(t[px][c]);
    }
}

// channels-last f32 [36864][128] -> planar f32 [128][36864]
__global__ __launch_bounds__(256)
void cl2p_kernel(const float* __restrict__ in, float* __restrict__ out)
{
    __shared__ float t[32][130];
    const int tid = threadIdx.x;
    const int p0 = blockIdx.x * 32;
#pragma unroll
    for (int j = 0; j < 16; ++j) {
        int idx = j * 256 + tid;
        int px = idx >> 7, c = idx & 127;
        t[px][c] = in[(size_t)(p0 + px) * 128 + c];
    }
    __syncthreads();
#pragma unroll
    for (int j = 0; j < 16; ++j) {
        int c = j * 8 + (tid >> 5);
        int px = tid & 31;
        out[(size_t)c * 36864 + p0 + px] = t[px][c];
    }
}

// ---------------- patch builders (h6 is channels-last bf16) -----------------
__global__ void build_patches_T(const u16* __restrict__ h6, const float* __restrict__ mask,
                                u16* __restrict__ fgpT, u16* __restrict__ bgpT)
{
    int idx = blockIdx.x * 256 + threadIdx.x;   // p*1152 + k
    if (idx >= 9216 * 1152) return;
    int p = idx / 1152, k = idx - p * 1152;
    int y = p / 96, x = p - y * 96;
    int c = k / 9, t = k - c * 9;
    int dy = t / 3, dx = t - dy * 3;
    int sy = y + dy - 1, sx = x + dx - 1;
    float v = 0.f, vm = 0.f;
    if (sy >= 0 && sy < 96 && sx >= 0 && sx < 96) {
        v  = bf2f(h6[((size_t)(2 * sy) * 192 + 2 * sx) * 128 + c]);
        vm = v * mask[(size_t)(2 * sy) * 192 + 2 * sx];
    }
    bgpT[idx] = f2bf(v);
    fgpT[idx] = f2bf(vm);
}

__global__ void build_patches_K(const u16* __restrict__ h6, const float* __restrict__ mask,
                                u16* __restrict__ fgpK, u16* __restrict__ bgpK)
{
    int idx = blockIdx.x * 256 + threadIdx.x;   // k*9216 + q
    if (idx >= 9216 * 1152) return;
    int k = idx / 9216, q = idx - k * 9216;
    int y = q / 96, x = q - y * 96;
    int c = k / 9, t = k - c * 9;
    int dy = t / 3, dx = t - dy * 3;
    int sy = y + dy - 1, sx = x + dx - 1;
    float v = 0.f, vm = 0.f;
    if (sy >= 0 && sy < 96 && sx >= 0 && sx < 96) {
        v  = bf2f(h6[((size_t)(2 * sy) * 192 + 2 * sx) * 128 + c]);
        vm = v * mask[(size_t)(2 * sy) * 192 + 2 * sx];
    }
    bgpK[idx] = f2bf(v);
    fgpK[idx] = f2bf(vm);
}

// ---------------- unified bf16 NT MFMA GEMM (attention) ---------------------
// D[m][n] = sum_k A[m][k]*B[n][k]; 128x128 tile, 4 waves, BK=64.
// EPI: 0 = fp32 store (Gram), 1 = exp(scale*v)->bf16 (S), 2 = fp32 += (PV)
template<int EPI>
__global__ __launch_bounds__(256)
void mfma_nt_kernel(const u16* __restrict__ A, const u16* __restrict__ B,
                    int lda, int ldb, int K,
                    float* __restrict__ outF, u16* __restrict__ outH, int ldo,
                    const float* __restrict__ scale_p)
{
    __shared__ u16 As[128 * 64];
    __shared__ u16 Bs[128 * 64];
    const int tid  = threadIdx.x;
    const int wid  = tid >> 6;
    const int lane = tid & 63;
    const int wm = (wid >> 1) * 64;
    const int wn = (wid & 1) * 64;
    const size_t bm = (size_t)blockIdx.y * 128;
    const size_t bn = (size_t)blockIdx.x * 128;

    f32x4 acc[4][4];
#pragma unroll
    for (int i = 0; i < 4; ++i)
#pragma unroll
        for (int j = 0; j < 4; ++j)
            acc[i][j] = (f32x4){0.f, 0.f, 0.f, 0.f};

    const int srow = tid >> 3;
    const int skb  = (tid & 7) * 16;

    for (int k0 = 0; k0 < K; k0 += 64) {
        short8v ra[4], rb[4];
#pragma unroll
        for (int i = 0; i < 4; ++i) {
            int m = srow + i * 32;
            ra[i] = *(const short8v*)((const char*)A + ((size_t)(bm + m) * lda + k0) * 2 + skb);
            rb[i] = *(const short8v*)((const char*)B + ((size_t)(bn + m) * ldb + k0) * 2 + skb);
        }
        __syncthreads();
#pragma unroll
        for (int i = 0; i < 4; ++i) {
            int m = srow + i * 32;
            int kbs = skb ^ ((m & 7) << 4);
            *(short8v*)((char*)As + m * 128 + kbs) = ra[i];
            *(short8v*)((char*)Bs + m * 128 + kbs) = rb[i];
        }
        __syncthreads();
#pragma unroll
        for (int ks = 0; ks < 2; ++ks) {
            short8v a[4], b[4];
#pragma unroll
            for (int f = 0; f < 4; ++f) {
                int ma = wm + f * 16 + (lane & 15);
                int kba = (ks * 64 + ((lane >> 4) * 16)) ^ ((ma & 7) << 4);
                a[f] = *(const short8v*)((const char*)As + ma * 128 + kba);
                int nb = wn + f * 16 + (lane & 15);
                int kbb = (ks * 64 + ((lane >> 4) * 16)) ^ ((nb & 7) << 4);
                b[f] = *(const short8v*)((const char*)Bs + nb * 128 + kbb);
            }
#pragma unroll
            for (int fm = 0; fm < 4; ++fm)
#pragma unroll
                for (int fn = 0; fn < 4; ++fn)
                    acc[fm][fn] = __builtin_amdgcn_mfma_f32_16x16x32_bf16(
                        a[fm], b[fn], acc[fm][fn], 0, 0, 0);
        }
    }

    const float scale = (EPI == 1) ? *scale_p : 0.f;
#pragma unroll
    for (int fm = 0; fm < 4; ++fm) {
#pragma unroll
        for (int fn = 0; fn < 4; ++fn) {
#pragma unroll
            for (int i = 0; i < 4; ++i) {
                int r = wm + fm * 16 + ((lane >> 4) * 4) + i;
                int c = wn + fn * 16 + (lane & 15);
                float v = acc[fm][fn][i];
                if (EPI == 0) {
                    outF[(bm + r) * (size_t)ldo + bn + c] = v;
                } else if (EPI == 1) {
                    outH[(bm + r) * (size_t)ldo + bn + c] = f2bf(__expf(scale * v));
                } else {
                    outF[(bm + r) * (size_t)ldo + bn + c] += v;
                }
            }
        }
    }
}

// ---------------- norm reductions ------------------------------------------
__global__ void dot_stage1(const float* __restrict__ a, const float* __restrict__ b,
                           double* __restrict__ partial, size_t n)
{
    size_t i = (size_t)blockIdx.x * 256 + threadIdx.x;
    size_t stride = (size_t)gridDim.x * 256;
    double s = 0.0;
    for (; i < n; i += stride) s += (double)a[i] * (double)b[i];
    for (int off = 32; off; off >>= 1) s += __shfl_down(s, off, 64);
    __shared__ double wsum[4];
    int lane = threadIdx.x & 63, wid = threadIdx.x >> 6;
    if (lane == 0) wsum[wid] = s;
    __syncthreads();
    if (threadIdx.x == 0) partial[blockIdx.x] = wsum[0] + wsum[1] + wsum[2] + wsum[3];
}

__global__ void sumsq_stage2(const double* __restrict__ partial, int nblocks, float* __restrict__ scale)
{
    double s = 0.0;
    for (int i = threadIdx.x; i < nblocks; i += 256) s += partial[i];
    for (int off = 32; off; off >>= 1) s += __shfl_down(s, off, 64);
    __shared__ double wsum[4];
    int lane = threadIdx.x & 63, wid = threadIdx.x >> 6;
    if (lane == 0) wsum[wid] = s;
    __syncthreads();
    if (threadIdx.x == 0) {
        double nrm = sqrt(wsum[0] + wsum[1] + wsum[2] + wsum[3]);
        if (nrm < 1e-12) nrm = 1e-12;
        *scale = (float)(10.0 / nrm);
    }
}

__global__ void rowsum_accum(const u16* __restrict__ P, float* __restrict__ rs)
{
    int wid = threadIdx.x >> 6, lane = threadIdx.x & 63;
    int row = blockIdx.x * 4 + wid;   // grid 2304
    const u16* rp = P + (size_t)row * 1536;
    float s = 0.f;
#pragma unroll
    for (int j = 0; j < 3; ++j) {
        short8v v = *(const short8v*)(rp + j * 512 + lane * 8);
#pragma unroll
        for (int e = 0; e < 8; ++e) s += bf2f((u16)v[e]);
    }
    for (int off = 32; off; off >>= 1) s += __shfl_down(s, off, 64);
    if (lane == 0) rs[row] += s;
}

__global__ void inv_kernel(const float* __restrict__ rs, float* __restrict__ inv)
{
    int i = blockIdx.x * 256 + threadIdx.x;
    if (i < 9216) inv[i] = 1.f / rs[i];
}

// ---------------- fold + mask + upsample (planar fp32 out) ------------------
__global__ void fold_mask_up_kernel(const float* __restrict__ R2,
                                    const float* __restrict__ inv,
                                    const float* __restrict__ mask,
                                    float* __restrict__ up)
{
    int idx = blockIdx.x * 256 + threadIdx.x; // 128*96*96
    if (idx >= 128 * 96 * 96) return;
    int x = idx % 96;
    int y = (idx / 96) % 96;
    int c = idx / (96 * 96);
    float s = 0.f;
#pragma unroll
    for (int dy = 0; dy < 3; ++dy) {
        int yy = y + 1 - dy;
        if (yy < 0 || yy >= 96) continue;
#pragma unroll
        for (int dx = 0; dx < 3; ++dx) {
            int xx = x + 1 - dx;
            if (xx < 0 || xx >= 96) continue;
            int pp = yy * 96 + xx;
            s += R2[(size_t)(c * 9 + dy * 3 + dx) * 9216 + pp] * inv[pp];
        }
    }
    s *= mask[(size_t)(2 * y) * 192 + 2 * x];
    size_t base = (size_t)c * 192 * 192;
    up[base + (size_t)(2 * y) * 192 + 2 * x]         = s;
    up[base + (size_t)(2 * y) * 192 + 2 * x + 1]     = s;
    up[base + (size_t)(2 * y + 1) * 192 + 2 * x]     = s;
    up[base + (size_t)(2 * y + 1) * 192 + 2 * x + 1] = s;
}

// ---------------------------------------------------------------------------
extern "C" void kernel_launch(void* const* d_in, const int* in_sizes, int n_in,
                              void* d_out, int out_size, void* d_ws, size_t ws_size,
                              hipStream_t stream)
{
    const float* x    = (const float*)d_in[0];
    const float* mask = (const float*)d_in[1];
    const float* w[8];
    const float* b[8];
    for (int i = 0; i < 8; ++i) {
        w[i] = (const float*)d_in[2 + 2 * i];
        b[i] = (const float*)d_in[3 + 2 * i];
    }
    char* ws = (char*)d_ws;
    dim3 blk(256);

    // byte offsets (see layout audit in analysis)
    const size_t F_H1   = 0;            // fp32 planar 32x768x768   (75,497,472)
    const size_t U_H2   = 75497472;     // cl bf16 384^2 x32        (9,437,184)
    const size_t U_H3   = 84934656;     // cl bf16 384^2 x64        (18,874,368)
    const size_t U_H4   = 103809024;    // cl bf16 192^2 x128       (9,437,184)
    const size_t U_H5   = 113246208;
    const size_t U_H6   = 122683392;    // ends 132,120,576
    const size_t U_WP3  = 132120576;    // 36,864
    const size_t U_WP4  = 132157440;    // 147,456
    const size_t U_WP5  = 132304896;    // 294,912
    const size_t U_WP6  = 132599808;
    const size_t U_WP7  = 132894720;
    const size_t U_WP8  = 133189632;    // ends 133,484,544
    const size_t U_FGPT = 0;            // 21,233,664 (over dead h1)
    const size_t U_BGPT = 21233664;
    const size_t U_FGPK = 42467328;
    const size_t U_BGPK = 63700992;     // ends 84,934,656
    const size_t F_R2   = 84934656;     // fp32 1152x9216 (42,467,328) over dead h3..h6
    const size_t U_P    = 133484544;    // bf16 9216x1536 (28,311,552)
    const size_t F_GF   = 161796096;    // 5,308,416
    const size_t F_GB   = 167104512;    // ends 172,412,928
    const size_t D_RED  = 172412928;    // 4,096
    const size_t F_SCALE= 172417024;
    const size_t F_RS   = 172417280;    // 36,864
    const size_t F_INV  = 172454144;    // ends 172,491,008  (peak)
    const size_t F_UP   = 0;            // fp32 planar 128x192x192 (18,874,368)
    const size_t U_UPCL = 18874368;     // cl bf16 (9,437,184)
    const size_t U_H7   = 28311552;     // cl bf16
    const size_t F_H8   = 37748736;     // cl fp32 (18,874,368) ends 56,623,104

    float* h1   = (float*)(ws + F_H1);
    u16* h2     = (u16*)(ws + U_H2);
    u16* h3     = (u16*)(ws + U_H3);
    u16* h4     = (u16*)(ws + U_H4);
    u16* h5     = (u16*)(ws + U_H5);
    u16* h6     = (u16*)(ws + U_H6);
    u16* wp3    = (u16*)(ws + U_WP3);
    u16* wp4    = (u16*)(ws + U_WP4);
    u16* wp5    = (u16*)(ws + U_WP5);
    u16* wp6    = (u16*)(ws + U_WP6);
    u16* wp7    = (u16*)(ws + U_WP7);
    u16* wp8    = (u16*)(ws + U_WP8);
    u16* fgpT   = (u16*)(ws + U_FGPT);
    u16* bgpT   = (u16*)(ws + U_BGPT);
    u16* fgpK   = (u16*)(ws + U_FGPK);
    u16* bgpK   = (u16*)(ws + U_BGPK);
    float* R2   = (float*)(ws + F_R2);
    u16* P      = (u16*)(ws + U_P);
    float* GF   = (float*)(ws + F_GF);
    float* GB   = (float*)(ws + F_GB);
    double* red = (double*)(ws + D_RED);
    float* scale= (float*)(ws + F_SCALE);
    float* rs   = (float*)(ws + F_RS);
    float* inv  = (float*)(ws + F_INV);
    float* upP  = (float*)(ws + F_UP);
    u16* upCL   = (u16*)(ws + U_UPCL);
    u16* h7     = (u16*)(ws + U_H7);
    float* h8   = (float*)(ws + F_H8);

    // ---- weight prepack (w3..w8) ----
    pack_w_kernel<<<dim3(72),  blk, 0, stream>>>(w[2], wp3, 64, 32);
    pack_w_kernel<<<dim3(288), blk, 0, stream>>>(w[3], wp4, 128, 64);
    pack_w_kernel<<<dim3(576), blk, 0, stream>>>(w[4], wp5, 128, 128);
    pack_w_kernel<<<dim3(576), blk, 0, stream>>>(w[5], wp6, 128, 128);
    pack_w_kernel<<<dim3(576), blk, 0, stream>>>(w[6], wp7, 128, 128);
    pack_w_kernel<<<dim3(576), blk, 0, stream>>>(w[7], wp8, 128, 128);

    // ---- conv front-end ----
    // conv1: direct fp32, planar out
    conv2d_kernel<5, 1, 1, 3, 0><<<dim3(48, 48, 4), blk, 0, stream>>>(
        x, w[0], b[0], h1, 3, 32, 768, 768, 768, 768, 2);
    // conv2: direct fp32 in, ch-last bf16 out
    conv2d_kernel<3, 2, 1, 8, 1><<<dim3(24, 24, 4), blk, 0, stream>>>(
        h1, w[1], b[1], h2, 32, 32, 768, 768, 384, 384, 1);
    // conv3: MFMA, 32->64, s1, 384^2
    mfma_conv_kernel<4, 2, 2, 2, 1, 32, 32, 1, 0><<<dim3(24, 48), blk, 0, stream>>>(
        h2, wp3, b[2], h3, 384, 384, 384, 384, 64);
    // conv4: MFMA, 64->128, s2, 384 -> 192 (ICC=32 keeps LDS under 64KB)
    mfma_conv_kernel<4, 4, 2, 2, 2, 64, 32, 1, 0><<<dim3(12, 24), blk, 0, stream>>>(
        h3, wp4, b[3], h4, 384, 384, 192, 192, 128);
    // conv5: MFMA, 128->128, s1, ELU
    mfma_conv_kernel<4, 4, 2, 2, 1, 128, 128, 1, 0><<<dim3(12, 24), blk, 0, stream>>>(
        h4, wp5, b[4], h5, 192, 192, 192, 192, 128);
    // conv6: MFMA, 128->128, s1, ReLU
    mfma_conv_kernel<4, 4, 2, 2, 1, 128, 128, 0, 0><<<dim3(12, 24), blk, 0, stream>>>(
        h5, wp6, b[5], h6, 192, 192, 192, 192, 128);

    // ---- patch matrices ----
    build_patches_T<<<dim3(41472), blk, 0, stream>>>(h6, mask, fgpT, bgpT);
    build_patches_K<<<dim3(41472), blk, 0, stream>>>(h6, mask, fgpK, bgpK);

    // ---- norm scale via Gram trick ----
    mfma_nt_kernel<0><<<dim3(9, 9), blk, 0, stream>>>(
        fgpK, fgpK, 9216, 9216, 9216, GF, nullptr, 1152, nullptr);
    mfma_nt_kernel<0><<<dim3(9, 9), blk, 0, stream>>>(
        bgpK, bgpK, 9216, 9216, 9216, GB, nullptr, 1152, nullptr);
    dot_stage1<<<dim3(512), blk, 0, stream>>>(GF, GB, red, (size_t)1152 * 1152);
    sumsq_stage2<<<dim3(1), blk, 0, stream>>>(red, 512, scale);

    // ---- zero accumulators ----
    hipMemsetAsync(R2, 0, (size_t)1152 * 9216 * 4, stream);
    hipMemsetAsync(rs, 0, 9216 * 4, stream);

    // ---- 6 q-stripes ----
    for (int s = 0; s < 6; ++s) {
        size_t qs = (size_t)s * 1536;
        mfma_nt_kernel<1><<<dim3(12, 72), blk, 0, stream>>>(
            fgpT, bgpT + qs * 1152, 1152, 1152, 1152, nullptr, P, 1536, scale);
        rowsum_accum<<<dim3(2304), blk, 0, stream>>>(P, rs);
        mfma_nt_kernel<2><<<dim3(72, 9), blk, 0, stream>>>(
            bgpK + qs, P, 9216, 1536, 1536, R2, nullptr, 9216, nullptr);
    }
    inv_kernel<<<dim3(36), blk, 0, stream>>>(rs, inv);
    fold_mask_up_kernel<<<dim3(4608), blk, 0, stream>>>(R2, inv, mask, upP);

    // ---- back-end convs ----
    p2cl_kernel<<<dim3(1152), blk, 0, stream>>>(upP, upCL);
    mfma_conv_kernel<4, 4, 2, 2, 1, 128, 128, 1, 0><<<dim3(12, 24), blk, 0, stream>>>(
        upCL, wp7, b[6], h7, 192, 192, 192, 192, 128);
    mfma_conv_kernel<4, 4, 2, 2, 1, 128, 128, 1, 1><<<dim3(12, 24), blk, 0, stream>>>(
        h7, wp8, b[7], h8, 192, 192, 192, 192, 128);
    cl2p_kernel<<<dim3(1152), blk, 0, stream>>>(h8, (float*)d_out);
}

// Round 5
// 1284.929 us; speedup vs baseline: 10.3791x; 1.2819x over previous
//
#include <hip/hip_runtime.h>
#include <math.h>

// ---------------------------------------------------------------------------
// Round 4->5: conv1 all-OC direct (bf16-cl out), conv2 MFMA implicit-GEMM,
// Gram merged+split-K (648 blocks). Attention stripes unchanged.
// Workspace peak 179.46 MB (< 180.56 MB proven safe).
// ---------------------------------------------------------------------------

typedef unsigned short u16;
typedef short short8v __attribute__((ext_vector_type(8)));
typedef float f32x4 __attribute__((ext_vector_type(4)));

__device__ __forceinline__ u16 f2bf(float f) {
    unsigned u = __float_as_uint(f);
    return (u16)((u + 0x7FFF + ((u >> 16) & 1)) >> 16);
}
__device__ __forceinline__ float bf2f(u16 h) {
    return __uint_as_float(((unsigned)h) << 16);
}

// ---------------- conv1: 3->32, 5x5, s1, reflect pad 2, ELU, bf16-cl out ----
__global__ __launch_bounds__(256)
void conv1_kernel(const float* __restrict__ in, const float* __restrict__ wgt,
                  const float* __restrict__ bias, u16* __restrict__ out)
{
    __shared__ float sIn[3][20][20];
    const int tid = threadIdx.x;
    const int tx = tid & 15, ty = tid >> 4;
    const int ox0 = blockIdx.x * 16, oy0 = blockIdx.y * 16;

    for (int i = tid; i < 3 * 20 * 20; i += 256) {
        int c = i / 400, rem = i - c * 400;
        int y = rem / 20, x = rem - y * 20;
        int gy = oy0 - 2 + y; gy = gy < 0 ? -gy : (gy >= 768 ? 1534 - gy : gy);
        int gx = ox0 - 2 + x; gx = gx < 0 ? -gx : (gx >= 768 ? 1534 - gx : gx);
        sIn[c][y][x] = in[(size_t)c * 589824 + (size_t)gy * 768 + gx];
    }
    __syncthreads();

    float acc[32];
#pragma unroll
    for (int o = 0; o < 32; ++o) acc[o] = 0.f;

#pragma unroll
    for (int ic = 0; ic < 3; ++ic)
#pragma unroll
        for (int ky = 0; ky < 5; ++ky)
#pragma unroll
            for (int kx = 0; kx < 5; ++kx) {
                float v = sIn[ic][ty + ky][tx + kx];
                const int off = ic * 25 + ky * 5 + kx;
#pragma unroll
                for (int o = 0; o < 32; ++o)
                    acc[o] = fmaf(v, wgt[o * 75 + off], acc[o]);
            }

    short8v ov[4];
#pragma unroll
    for (int o = 0; o < 32; ++o) {
        float v = acc[o] + bias[o];
        v = v > 0.f ? v : expm1f(v);
        ((u16*)ov)[o] = f2bf(v);
    }
    size_t base = ((size_t)(oy0 + ty) * 768 + ox0 + tx) * 32;
#pragma unroll
    for (int k = 0; k < 4; ++k)
        *(short8v*)(out + base + k * 8) = ov[k];
}

// ---------------- weight prepack: [oc][ic][3][3] f32 -> [oc][tap][ic] bf16 --
__global__ void pack_w_kernel(const float* __restrict__ w, u16* __restrict__ wp,
                              int OC, int IC)
{
    int idx = blockIdx.x * 256 + threadIdx.x;
    if (idx >= OC * 9 * IC) return;
    int oc = idx / (9 * IC);
    int r  = idx - oc * 9 * IC;
    int tap = r / IC;
    int ic  = r - tap * IC;
    wp[idx] = f2bf(w[((size_t)oc * IC + ic) * 9 + tap]);
}

// ---------------- MFMA implicit-GEMM conv (3x3, reflect pad 1) --------------
template<int FM, int FN, int NWM, int NWN, int S, int IC, int ICC, int ACT, int OUTF32>
__global__ __launch_bounds__(256)
void mfma_conv_kernel(const u16* __restrict__ in, const u16* __restrict__ wgtP,
                      const float* __restrict__ bias, void* __restrict__ out,
                      int H, int W, int Ho, int Wo, int OC)
{
    constexpr int TY = 7 * S + 3;
    constexpr int TX = 15 * S + 3;
    constexpr int NSLOT = ICC / 8;
    constexpr int SWMSK = NSLOT - 1;
    constexpr int KTOT = 9 * IC;
    __shared__ __align__(16) u16 sIn[TY * TX * ICC];

    const int tid  = threadIdx.x;
    const int lane = tid & 63;
    const int wid  = tid >> 6;
    const int wmi  = wid / NWN;
    const int wni  = wid % NWN;
    const int lm   = lane & 15;
    const int lk   = lane >> 4;

    f32x4 acc[FM][FN];
#pragma unroll
    for (int i = 0; i < FM; ++i)
#pragma unroll
        for (int j = 0; j < FN; ++j) acc[i][j] = (f32x4){0.f, 0.f, 0.f, 0.f};

    const int iy0 = blockIdx.y * 8 * S - 1;
    const int ix0 = blockIdx.x * 16 * S - 1;

    for (int c0 = 0; c0 < IC; c0 += ICC) {
        if (c0) __syncthreads();
        for (int u = tid; u < TY * TX * NSLOT; u += 256) {
            int yt = u / (TX * NSLOT);
            int r  = u - yt * (TX * NSLOT);
            int xt = r / NSLOT;
            int sl = r - xt * NSLOT;
            int gy = iy0 + yt; gy = gy < 0 ? -gy : (gy >= H ? 2 * H - 2 - gy : gy);
            int gx = ix0 + xt; gx = gx < 0 ? -gx : (gx >= W ? 2 * W - 2 - gx : gx);
            *(short8v*)((char*)sIn + (size_t)((yt * TX + xt) * NSLOT + (sl ^ (xt & SWMSK))) * 16) =
                *(const short8v*)(in + ((size_t)gy * W + gx) * IC + c0 + sl * 8);
        }
        __syncthreads();
#pragma unroll
        for (int tap = 0; tap < 9; ++tap) {
            const int dy = tap / 3, dx = tap % 3;
#pragma unroll
            for (int icw = 0; icw < ICC / 32; ++icw) {
                short8v a[FM], b[FN];
#pragma unroll
                for (int fm = 0; fm < FM; ++fm) {
                    int yt = (wmi * FM + fm) * S + dy;
                    int xt = lm * S + dx;
                    a[fm] = *(const short8v*)((const char*)sIn +
                        (size_t)((yt * TX + xt) * NSLOT + ((icw * 4 + lk) ^ (xt & SWMSK))) * 16);
                }
#pragma unroll
                for (int fn = 0; fn < FN; ++fn) {
                    int n = wni * FN * 16 + fn * 16 + lm;
                    b[fn] = *(const short8v*)(wgtP + (size_t)n * KTOT + tap * IC + c0 + icw * 32 + lk * 8);
                }
#pragma unroll
                for (int fm = 0; fm < FM; ++fm)
#pragma unroll
                    for (int fn = 0; fn < FN; ++fn)
                        acc[fm][fn] = __builtin_amdgcn_mfma_f32_16x16x32_bf16(
                            a[fm], b[fn], acc[fm][fn], 0, 0, 0);
            }
        }
    }

#pragma unroll
    for (int fm = 0; fm < FM; ++fm) {
        int y = blockIdx.y * 8 + wmi * FM + fm;
#pragma unroll
        for (int fn = 0; fn < FN; ++fn) {
            int oc = wni * FN * 16 + fn * 16 + lm;
            float bv = bias[oc];
#pragma unroll
            for (int i = 0; i < 4; ++i) {
                int x = blockIdx.x * 16 + lk * 4 + i;
                float v = acc[fm][fn][i] + bv;
                if (ACT == 0) v = v > 0.f ? v : 0.f;
                else          v = v > 0.f ? v : expm1f(v);
                size_t o = ((size_t)y * Wo + x) * OC + oc;
                if (OUTF32) ((float*)out)[o] = v;
                else        ((u16*)out)[o]   = f2bf(v);
            }
        }
    }
}

// channels-last f32 [36864][128] -> planar f32 [128][36864]
__global__ __launch_bounds__(256)
void cl2p_kernel(const float* __restrict__ in, float* __restrict__ out)
{
    __shared__ float t[32][130];
    const int tid = threadIdx.x;
    const int p0 = blockIdx.x * 32;
#pragma unroll
    for (int j = 0; j < 16; ++j) {
        int idx = j * 256 + tid;
        int px = idx >> 7, c = idx & 127;
        t[px][c] = in[(size_t)(p0 + px) * 128 + c];
    }
    __syncthreads();
#pragma unroll
    for (int j = 0; j < 16; ++j) {
        int c = j * 8 + (tid >> 5);
        int px = tid & 31;
        out[(size_t)c * 36864 + p0 + px] = t[px][c];
    }
}

// planar f32 [128][36864] -> channels-last bf16 [36864][128]
__global__ __launch_bounds__(256)
void p2cl_kernel(const float* __restrict__ in, u16* __restrict__ out)
{
    __shared__ float t[32][130];
    const int tid = threadIdx.x;
    const int p0 = blockIdx.x * 32;
#pragma unroll
    for (int j = 0; j < 16; ++j) {
        int c = j * 8 + (tid >> 5);
        int px = tid & 31;
        t[px][c] = in[(size_t)c * 36864 + p0 + px];
    }
    __syncthreads();
#pragma unroll
    for (int j = 0; j < 16; ++j) {
        int idx = j * 256 + tid;
        int px = idx >> 7, c = idx & 127;
        out[(size_t)(p0 + px) * 128 + c] = f2bf(t[px][c]);
    }
}

// ---------------- patch builders (h6 is channels-last bf16) -----------------
__global__ void build_patches_T(const u16* __restrict__ h6, const float* __restrict__ mask,
                                u16* __restrict__ fgpT, u16* __restrict__ bgpT)
{
    int idx = blockIdx.x * 256 + threadIdx.x;   // p*1152 + k
    if (idx >= 9216 * 1152) return;
    int p = idx / 1152, k = idx - p * 1152;
    int y = p / 96, x = p - y * 96;
    int c = k / 9, t = k - c * 9;
    int dy = t / 3, dx = t - dy * 3;
    int sy = y + dy - 1, sx = x + dx - 1;
    float v = 0.f, vm = 0.f;
    if (sy >= 0 && sy < 96 && sx >= 0 && sx < 96) {
        v  = bf2f(h6[((size_t)(2 * sy) * 192 + 2 * sx) * 128 + c]);
        vm = v * mask[(size_t)(2 * sy) * 192 + 2 * sx];
    }
    bgpT[idx] = f2bf(v);
    fgpT[idx] = f2bf(vm);
}

__global__ void build_patches_K(const u16* __restrict__ h6, const float* __restrict__ mask,
                                u16* __restrict__ fgpK, u16* __restrict__ bgpK)
{
    int idx = blockIdx.x * 256 + threadIdx.x;   // k*9216 + q
    if (idx >= 9216 * 1152) return;
    int k = idx / 9216, q = idx - k * 9216;
    int y = q / 96, x = q - y * 96;
    int c = k / 9, t = k - c * 9;
    int dy = t / 3, dx = t - dy * 3;
    int sy = y + dy - 1, sx = x + dx - 1;
    float v = 0.f, vm = 0.f;
    if (sy >= 0 && sy < 96 && sx >= 0 && sx < 96) {
        v  = bf2f(h6[((size_t)(2 * sy) * 192 + 2 * sx) * 128 + c]);
        vm = v * mask[(size_t)(2 * sy) * 192 + 2 * sx];
    }
    bgpK[idx] = f2bf(v);
    fgpK[idx] = f2bf(vm);
}

// ---------------- unified bf16 NT MFMA GEMM (attention) ---------------------
// EPI: 1 = exp(scale*v)->bf16 (S), 2 = fp32 += (PV)
template<int EPI>
__global__ __launch_bounds__(256)
void mfma_nt_kernel(const u16* __restrict__ A, const u16* __restrict__ B,
                    int lda, int ldb, int K,
                    float* __restrict__ outF, u16* __restrict__ outH, int ldo,
                    const float* __restrict__ scale_p)
{
    __shared__ u16 As[128 * 64];
    __shared__ u16 Bs[128 * 64];
    const int tid  = threadIdx.x;
    const int wid  = tid >> 6;
    const int lane = tid & 63;
    const int wm = (wid >> 1) * 64;
    const int wn = (wid & 1) * 64;
    const size_t bm = (size_t)blockIdx.y * 128;
    const size_t bn = (size_t)blockIdx.x * 128;

    f32x4 acc[4][4];
#pragma unroll
    for (int i = 0; i < 4; ++i)
#pragma unroll
        for (int j = 0; j < 4; ++j)
            acc[i][j] = (f32x4){0.f, 0.f, 0.f, 0.f};

    const int srow = tid >> 3;
    const int skb  = (tid & 7) * 16;

    for (int k0 = 0; k0 < K; k0 += 64) {
        short8v ra[4], rb[4];
#pragma unroll
        for (int i = 0; i < 4; ++i) {
            int m = srow + i * 32;
            ra[i] = *(const short8v*)((const char*)A + ((size_t)(bm + m) * lda + k0) * 2 + skb);
            rb[i] = *(const short8v*)((const char*)B + ((size_t)(bn + m) * ldb + k0) * 2 + skb);
        }
        __syncthreads();
#pragma unroll
        for (int i = 0; i < 4; ++i) {
            int m = srow + i * 32;
            int kbs = skb ^ ((m & 7) << 4);
            *(short8v*)((char*)As + m * 128 + kbs) = ra[i];
            *(short8v*)((char*)Bs + m * 128 + kbs) = rb[i];
        }
        __syncthreads();
#pragma unroll
        for (int ks = 0; ks < 2; ++ks) {
            short8v a[4], b[4];
#pragma unroll
            for (int f = 0; f < 4; ++f) {
                int ma = wm + f * 16 + (lane & 15);
                int kba = (ks * 64 + ((lane >> 4) * 16)) ^ ((ma & 7) << 4);
                a[f] = *(const short8v*)((const char*)As + ma * 128 + kba);
                int nb = wn + f * 16 + (lane & 15);
                int kbb = (ks * 64 + ((lane >> 4) * 16)) ^ ((nb & 7) << 4);
                b[f] = *(const short8v*)((const char*)Bs + nb * 128 + kbb);
            }
#pragma unroll
            for (int fm = 0; fm < 4; ++fm)
#pragma unroll
                for (int fn = 0; fn < 4; ++fn)
                    acc[fm][fn] = __builtin_amdgcn_mfma_f32_16x16x32_bf16(
                        a[fm], b[fn], acc[fm][fn], 0, 0, 0);
        }
    }

    const float scale = (EPI == 1) ? *scale_p : 0.f;
#pragma unroll
    for (int fm = 0; fm < 4; ++fm) {
#pragma unroll
        for (int fn = 0; fn < 4; ++fn) {
#pragma unroll
            for (int i = 0; i < 4; ++i) {
                int r = wm + fm * 16 + ((lane >> 4) * 4) + i;
                int c = wn + fn * 16 + (lane & 15);
                float v = acc[fm][fn][i];
                if (EPI == 1) {
                    outH[(bm + r) * (size_t)ldo + bn + c] = f2bf(__expf(scale * v));
                } else {
                    outF[(bm + r) * (size_t)ldo + bn + c] += v;
                }
            }
        }
    }
}

// ---------------- Gram kernel: grid (9,9,8); z = pair*4 + splitK ------------
// GP[z] = 128x128 tile of (A A^T) over K chunk [split*2304, +2304), A = fg/bg.
__global__ __launch_bounds__(256)
void gram_kernel(const u16* __restrict__ F, const u16* __restrict__ Bg,
                 float* __restrict__ GP)
{
    const u16* A = (blockIdx.z >> 2) ? Bg : F;
    const int split = blockIdx.z & 3;
    __shared__ u16 As[128 * 64];
    __shared__ u16 Bs[128 * 64];
    const int tid  = threadIdx.x;
    const int wid  = tid >> 6;
    const int lane = tid & 63;
    const int wm = (wid >> 1) * 64;
    const int wn = (wid & 1) * 64;
    const size_t bm = (size_t)blockIdx.y * 128;
    const size_t bn = (size_t)blockIdx.x * 128;

    f32x4 acc[4][4];
#pragma unroll
    for (int i = 0; i < 4; ++i)
#pragma unroll
        for (int j = 0; j < 4; ++j)
            acc[i][j] = (f32x4){0.f, 0.f, 0.f, 0.f};

    const int srow = tid >> 3;
    const int skb  = (tid & 7) * 16;
    const int kbeg = split * 2304;

    for (int k0 = kbeg; k0 < kbeg + 2304; k0 += 64) {
        short8v ra[4], rb[4];
#pragma unroll
        for (int i = 0; i < 4; ++i) {
            int m = srow + i * 32;
            ra[i] = *(const short8v*)((const char*)A + ((size_t)(bm + m) * 9216 + k0) * 2 + skb);
            rb[i] = *(const short8v*)((const char*)A + ((size_t)(bn + m) * 9216 + k0) * 2 + skb);
        }
        __syncthreads();
#pragma unroll
        for (int i = 0; i < 4; ++i) {
            int m = srow + i * 32;
            int kbs = skb ^ ((m & 7) << 4);
            *(short8v*)((char*)As + m * 128 + kbs) = ra[i];
            *(short8v*)((char*)Bs + m * 128 + kbs) = rb[i];
        }
        __syncthreads();
#pragma unroll
        for (int ks = 0; ks < 2; ++ks) {
            short8v a[4], b[4];
#pragma unroll
            for (int f = 0; f < 4; ++f) {
                int ma = wm + f * 16 + (lane & 15);
                int kba = (ks * 64 + ((lane >> 4) * 16)) ^ ((ma & 7) << 4);
                a[f] = *(const short8v*)((const char*)As + ma * 128 + kba);
                int nb = wn + f * 16 + (lane & 15);
                int kbb = (ks * 64 + ((lane >> 4) * 16)) ^ ((nb & 7) << 4);
                b[f] = *(const short8v*)((const char*)Bs + nb * 128 + kbb);
            }
#pragma unroll
            for (int fm = 0; fm < 4; ++fm)
#pragma unroll
                for (int fn = 0; fn < 4; ++fn)
                    acc[fm][fn] = __builtin_amdgcn_mfma_f32_16x16x32_bf16(
                        a[fm], b[fn], acc[fm][fn], 0, 0, 0);
        }
    }

    float* out = GP + (size_t)blockIdx.z * 1327104;
#pragma unroll
    for (int fm = 0; fm < 4; ++fm)
#pragma unroll
        for (int fn = 0; fn < 4; ++fn)
#pragma unroll
            for (int i = 0; i < 4; ++i) {
                int r = wm + fm * 16 + ((lane >> 4) * 4) + i;
                int c = wn + fn * 16 + (lane & 15);
                out[(bm + r) * 1152 + bn + c] = acc[fm][fn][i];
            }
}

// dot over summed split-K partials: sum_i (sum_s GF_s[i]) * (sum_s GB_s[i])
__global__ void dot_gram_stage1(const float* __restrict__ GP, double* __restrict__ partial)
{
    const size_t n = 1327104;
    size_t i = (size_t)blockIdx.x * 256 + threadIdx.x;
    size_t stride = (size_t)gridDim.x * 256;
    double s = 0.0;
    for (; i < n; i += stride) {
        float gf = GP[i] + GP[n + i] + GP[2 * n + i] + GP[3 * n + i];
        float gb = GP[4 * n + i] + GP[5 * n + i] + GP[6 * n + i] + GP[7 * n + i];
        s += (double)gf * (double)gb;
    }
    for (int off = 32; off; off >>= 1) s += __shfl_down(s, off, 64);
    __shared__ double wsum[4];
    int lane = threadIdx.x & 63, wid = threadIdx.x >> 6;
    if (lane == 0) wsum[wid] = s;
    __syncthreads();
    if (threadIdx.x == 0) partial[blockIdx.x] = wsum[0] + wsum[1] + wsum[2] + wsum[3];
}

__global__ void sumsq_stage2(const double* __restrict__ partial, int nblocks, float* __restrict__ scale)
{
    double s = 0.0;
    for (int i = threadIdx.x; i < nblocks; i += 256) s += partial[i];
    for (int off = 32; off; off >>= 1) s += __shfl_down(s, off, 64);
    __shared__ double wsum[4];
    int lane = threadIdx.x & 63, wid = threadIdx.x >> 6;
    if (lane == 0) wsum[wid] = s;
    __syncthreads();
    if (threadIdx.x == 0) {
        double nrm = sqrt(wsum[0] + wsum[1] + wsum[2] + wsum[3]);
        if (nrm < 1e-12) nrm = 1e-12;
        *scale = (float)(10.0 / nrm);
    }
}

__global__ void rowsum_accum(const u16* __restrict__ P, float* __restrict__ rs)
{
    int wid = threadIdx.x >> 6, lane = threadIdx.x & 63;
    int row = blockIdx.x * 4 + wid;   // grid 2304
    const u16* rp = P + (size_t)row * 1536;
    float s = 0.f;
#pragma unroll
    for (int j = 0; j < 3; ++j) {
        short8v v = *(const short8v*)(rp + j * 512 + lane * 8);
#pragma unroll
        for (int e = 0; e < 8; ++e) s += bf2f((u16)v[e]);
    }
    for (int off = 32; off; off >>= 1) s += __shfl_down(s, off, 64);
    if (lane == 0) rs[row] += s;
}

__global__ void inv_kernel(const float* __restrict__ rs, float* __restrict__ inv)
{
    int i = blockIdx.x * 256 + threadIdx.x;
    if (i < 9216) inv[i] = 1.f / rs[i];
}

// ---------------- fold + mask + upsample (planar fp32 out) ------------------
__global__ void fold_mask_up_kernel(const float* __restrict__ R2,
                                    const float* __restrict__ inv,
                                    const float* __restrict__ mask,
                                    float* __restrict__ up)
{
    int idx = blockIdx.x * 256 + threadIdx.x; // 128*96*96
    if (idx >= 128 * 96 * 96) return;
    int x = idx % 96;
    int y = (idx / 96) % 96;
    int c = idx / (96 * 96);
    float s = 0.f;
#pragma unroll
    for (int dy = 0; dy < 3; ++dy) {
        int yy = y + 1 - dy;
        if (yy < 0 || yy >= 96) continue;
#pragma unroll
        for (int dx = 0; dx < 3; ++dx) {
            int xx = x + 1 - dx;
            if (xx < 0 || xx >= 96) continue;
            int pp = yy * 96 + xx;
            s += R2[(size_t)(c * 9 + dy * 3 + dx) * 9216 + pp] * inv[pp];
        }
    }
    s *= mask[(size_t)(2 * y) * 192 + 2 * x];
    size_t base = (size_t)c * 192 * 192;
    up[base + (size_t)(2 * y) * 192 + 2 * x]         = s;
    up[base + (size_t)(2 * y) * 192 + 2 * x + 1]     = s;
    up[base + (size_t)(2 * y + 1) * 192 + 2 * x]     = s;
    up[base + (size_t)(2 * y + 1) * 192 + 2 * x + 1] = s;
}

// ---------------------------------------------------------------------------
extern "C" void kernel_launch(void* const* d_in, const int* in_sizes, int n_in,
                              void* d_out, int out_size, void* d_ws, size_t ws_size,
                              hipStream_t stream)
{
    const float* x    = (const float*)d_in[0];
    const float* mask = (const float*)d_in[1];
    const float* w[8];
    const float* b[8];
    for (int i = 0; i < 8; ++i) {
        w[i] = (const float*)d_in[2 + 2 * i];
        b[i] = (const float*)d_in[3 + 2 * i];
    }
    char* ws = (char*)d_ws;
    dim3 blk(256);

    // byte offsets (liveness-audited)
    const size_t U_H1CL = 0;            // cl bf16 768^2 x32  (37,748,736)
    const size_t U_H2   = 37748736;     // cl bf16 384^2 x32  ( 9,437,184)
    const size_t U_H3   = 47185920;     // cl bf16 384^2 x64  (18,874,368)
    const size_t U_H4   = 66060288;     // cl bf16 192^2 x128 ( 9,437,184)
    const size_t U_H5   = 75497472;
    const size_t U_H6   = 84934656;     // ends 94,371,840
    const size_t U_FGPT = 0;            // 21,233,664 each (over dead h1cl..h5)
    const size_t U_BGPT = 21233664;
    const size_t U_FGPK = 42467328;
    const size_t U_BGPK = 63700992;     // ends 84,934,656 (== h6 start)
    const size_t F_GP   = 84934656;     // 8 x 1152^2 fp32 = 42,467,328 (over dead h6)
    const size_t F_R2   = 84934656;     // fp32 [1152][9216] (after GP dead)
    const size_t U_P    = 127401984;    // bf16 9216x1536 (28,311,552) -> 155,713,536
    const size_t F_UP   = 0;            // planar fp32 128x192^2 (18,874,368)
    const size_t U_UPCL = 18874368;     // cl bf16 ( 9,437,184)
    const size_t U_H7   = 28311552;     // cl bf16
    const size_t F_H8   = 37748736;     // cl fp32 (18,874,368) -> 56,623,104
    const size_t U_WP2  = 178000000;    //  18,432
    const size_t U_WP3  = 178018432;    //  36,864
    const size_t U_WP4  = 178055296;    // 147,456
    const size_t U_WP5  = 178202752;    // 294,912
    const size_t U_WP6  = 178497664;
    const size_t U_WP7  = 178792576;
    const size_t U_WP8  = 179087488;    // ends 179,382,400
    const size_t D_RED  = 179382400;    //   4,096
    const size_t F_SCALE= 179386496;
    const size_t F_RS   = 179386752;    //  36,864
    const size_t F_INV  = 179423616;    // ends 179,460,480 (peak)

    u16* h1cl   = (u16*)(ws + U_H1CL);
    u16* h2     = (u16*)(ws + U_H2);
    u16* h3     = (u16*)(ws + U_H3);
    u16* h4     = (u16*)(ws + U_H4);
    u16* h5     = (u16*)(ws + U_H5);
    u16* h6     = (u16*)(ws + U_H6);
    u16* fgpT   = (u16*)(ws + U_FGPT);
    u16* bgpT   = (u16*)(ws + U_BGPT);
    u16* fgpK   = (u16*)(ws + U_FGPK);
    u16* bgpK   = (u16*)(ws + U_BGPK);
    float* GP   = (float*)(ws + F_GP);
    float* R2   = (float*)(ws + F_R2);
    u16* P      = (u16*)(ws + U_P);
    float* upP  = (float*)(ws + F_UP);
    u16* upCL   = (u16*)(ws + U_UPCL);
    u16* h7     = (u16*)(ws + U_H7);
    float* h8   = (float*)(ws + F_H8);
    u16* wp2    = (u16*)(ws + U_WP2);
    u16* wp3    = (u16*)(ws + U_WP3);
    u16* wp4    = (u16*)(ws + U_WP4);
    u16* wp5    = (u16*)(ws + U_WP5);
    u16* wp6    = (u16*)(ws + U_WP6);
    u16* wp7    = (u16*)(ws + U_WP7);
    u16* wp8    = (u16*)(ws + U_WP8);
    double* red = (double*)(ws + D_RED);
    float* scale= (float*)(ws + F_SCALE);
    float* rs   = (float*)(ws + F_RS);
    float* inv  = (float*)(ws + F_INV);

    // ---- weight prepack ----
    pack_w_kernel<<<dim3(36),  blk, 0, stream>>>(w[1], wp2, 32, 32);
    pack_w_kernel<<<dim3(72),  blk, 0, stream>>>(w[2], wp3, 64, 32);
    pack_w_kernel<<<dim3(288), blk, 0, stream>>>(w[3], wp4, 128, 64);
    pack_w_kernel<<<dim3(576), blk, 0, stream>>>(w[4], wp5, 128, 128);
    pack_w_kernel<<<dim3(576), blk, 0, stream>>>(w[5], wp6, 128, 128);
    pack_w_kernel<<<dim3(576), blk, 0, stream>>>(w[6], wp7, 128, 128);
    pack_w_kernel<<<dim3(576), blk, 0, stream>>>(w[7], wp8, 128, 128);

    // ---- conv front-end ----
    conv1_kernel<<<dim3(48, 48), blk, 0, stream>>>(x, w[0], b[0], h1cl);
    // conv2: MFMA, 32->32, s2, 768 -> 384
    mfma_conv_kernel<4, 1, 2, 2, 2, 32, 32, 1, 0><<<dim3(24, 48), blk, 0, stream>>>(
        h1cl, wp2, b[1], h2, 768, 768, 384, 384, 32);
    // conv3: MFMA, 32->64, s1, 384^2
    mfma_conv_kernel<4, 2, 2, 2, 1, 32, 32, 1, 0><<<dim3(24, 48), blk, 0, stream>>>(
        h2, wp3, b[2], h3, 384, 384, 384, 384, 64);
    // conv4: MFMA, 64->128, s2, 384 -> 192
    mfma_conv_kernel<4, 4, 2, 2, 2, 64, 32, 1, 0><<<dim3(12, 24), blk, 0, stream>>>(
        h3, wp4, b[3], h4, 384, 384, 192, 192, 128);
    // conv5: MFMA, 128->128, s1, ELU
    mfma_conv_kernel<4, 4, 2, 2, 1, 128, 128, 1, 0><<<dim3(12, 24), blk, 0, stream>>>(
        h4, wp5, b[4], h5, 192, 192, 192, 192, 128);
    // conv6: MFMA, 128->128, s1, ReLU
    mfma_conv_kernel<4, 4, 2, 2, 1, 128, 128, 0, 0><<<dim3(12, 24), blk, 0, stream>>>(
        h5, wp6, b[5], h6, 192, 192, 192, 192, 128);

    // ---- patch matrices ----
    build_patches_T<<<dim3(41472), blk, 0, stream>>>(h6, mask, fgpT, bgpT);
    build_patches_K<<<dim3(41472), blk, 0, stream>>>(h6, mask, fgpK, bgpK);

    // ---- norm scale via Gram trick (merged fg/bg + split-K, 648 blocks) ----
    gram_kernel<<<dim3(9, 9, 8), blk, 0, stream>>>(fgpK, bgpK, GP);
    dot_gram_stage1<<<dim3(512), blk, 0, stream>>>(GP, red);
    sumsq_stage2<<<dim3(1), blk, 0, stream>>>(red, 512, scale);

    // ---- zero accumulators (GP dead; R2 reuses its region) ----
    hipMemsetAsync(R2, 0, (size_t)1152 * 9216 * 4, stream);
    hipMemsetAsync(rs, 0, 9216 * 4, stream);

    // ---- 6 q-stripes: S-exp -> P, rowsum accumulate, PV accumulate ----
    for (int s = 0; s < 6; ++s) {
        size_t qs = (size_t)s * 1536;
        mfma_nt_kernel<1><<<dim3(12, 72), blk, 0, stream>>>(
            fgpT, bgpT + qs * 1152, 1152, 1152, 1152, nullptr, P, 1536, scale);
        rowsum_accum<<<dim3(2304), blk, 0, stream>>>(P, rs);
        mfma_nt_kernel<2><<<dim3(72, 9), blk, 0, stream>>>(
            bgpK + qs, P, 9216, 1536, 1536, R2, nullptr, 9216, nullptr);
    }
    inv_kernel<<<dim3(36), blk, 0, stream>>>(rs, inv);
    fold_mask_up_kernel<<<dim3(4608), blk, 0, stream>>>(R2, inv, mask, upP);

    // ---- back-end convs ----
    p2cl_kernel<<<dim3(1152), blk, 0, stream>>>(upP, upCL);
    mfma_conv_kernel<4, 4, 2, 2, 1, 128, 128, 1, 0><<<dim3(12, 24), blk, 0, stream>>>(
        upCL, wp7, b[6], h7, 192, 192, 192, 192, 128);
    mfma_conv_kernel<4, 4, 2, 2, 1, 128, 128, 1, 1><<<dim3(12, 24), blk, 0, stream>>>(
        h7, wp8, b[7], h8, 192, 192, 192, 192, 128);
    cl2p_kernel<<<dim3(1152), blk, 0, stream>>>(h8, (float*)d_out);
}

// Round 6
// 1204.094 us; speedup vs baseline: 11.0759x; 1.0671x over previous
//
#include <hip/hip_runtime.h>
#include <math.h>

// ---------------------------------------------------------------------------
// Round 5->6: global_load_lds (width 16) staging in attention GEMMs (linear
// LDS dest + inverse-swizzled global source + swizzled read), rowsum fused
// into sexp epilogue (deterministic per-wave-half partials), PV stripe-0
// stores (no R2 memset). Convs/patches unchanged.
// ---------------------------------------------------------------------------

typedef unsigned short u16;
typedef short short8v __attribute__((ext_vector_type(8)));
typedef float f32x4 __attribute__((ext_vector_type(4)));

__device__ __forceinline__ u16 f2bf(float f) {
    unsigned u = __float_as_uint(f);
    return (u16)((u + 0x7FFF + ((u >> 16) & 1)) >> 16);
}
__device__ __forceinline__ float bf2f(u16 h) {
    return __uint_as_float(((unsigned)h) << 16);
}

#define GLOAD16(g, l) __builtin_amdgcn_global_load_lds(                      \
    (const __attribute__((address_space(1))) void*)(g),                      \
    (__attribute__((address_space(3))) void*)(l), 16, 0, 0)

// ---------------- conv1: 3->32, 5x5, s1, reflect pad 2, ELU, bf16-cl out ----
__global__ __launch_bounds__(256)
void conv1_kernel(const float* __restrict__ in, const float* __restrict__ wgt,
                  const float* __restrict__ bias, u16* __restrict__ out)
{
    __shared__ float sIn[3][20][20];
    const int tid = threadIdx.x;
    const int tx = tid & 15, ty = tid >> 4;
    const int ox0 = blockIdx.x * 16, oy0 = blockIdx.y * 16;

    for (int i = tid; i < 3 * 20 * 20; i += 256) {
        int c = i / 400, rem = i - c * 400;
        int y = rem / 20, x = rem - y * 20;
        int gy = oy0 - 2 + y; gy = gy < 0 ? -gy : (gy >= 768 ? 1534 - gy : gy);
        int gx = ox0 - 2 + x; gx = gx < 0 ? -gx : (gx >= 768 ? 1534 - gx : gx);
        sIn[c][y][x] = in[(size_t)c * 589824 + (size_t)gy * 768 + gx];
    }
    __syncthreads();

    float acc[32];
#pragma unroll
    for (int o = 0; o < 32; ++o) acc[o] = 0.f;

#pragma unroll
    for (int ic = 0; ic < 3; ++ic)
#pragma unroll
        for (int ky = 0; ky < 5; ++ky)
#pragma unroll
            for (int kx = 0; kx < 5; ++kx) {
                float v = sIn[ic][ty + ky][tx + kx];
                const int off = ic * 25 + ky * 5 + kx;
#pragma unroll
                for (int o = 0; o < 32; ++o)
                    acc[o] = fmaf(v, wgt[o * 75 + off], acc[o]);
            }

    short8v ov[4];
#pragma unroll
    for (int o = 0; o < 32; ++o) {
        float v = acc[o] + bias[o];
        v = v > 0.f ? v : expm1f(v);
        ((u16*)ov)[o] = f2bf(v);
    }
    size_t base = ((size_t)(oy0 + ty) * 768 + ox0 + tx) * 32;
#pragma unroll
    for (int k = 0; k < 4; ++k)
        *(short8v*)(out + base + k * 8) = ov[k];
}

// ---------------- weight prepack: [oc][ic][3][3] f32 -> [oc][tap][ic] bf16 --
__global__ void pack_w_kernel(const float* __restrict__ w, u16* __restrict__ wp,
                              int OC, int IC)
{
    int idx = blockIdx.x * 256 + threadIdx.x;
    if (idx >= OC * 9 * IC) return;
    int oc = idx / (9 * IC);
    int r  = idx - oc * 9 * IC;
    int tap = r / IC;
    int ic  = r - tap * IC;
    wp[idx] = f2bf(w[((size_t)oc * IC + ic) * 9 + tap]);
}

// ---------------- MFMA implicit-GEMM conv (3x3, reflect pad 1) --------------
template<int FM, int FN, int NWM, int NWN, int S, int IC, int ICC, int ACT, int OUTF32>
__global__ __launch_bounds__(256)
void mfma_conv_kernel(const u16* __restrict__ in, const u16* __restrict__ wgtP,
                      const float* __restrict__ bias, void* __restrict__ out,
                      int H, int W, int Ho, int Wo, int OC)
{
    constexpr int TY = 7 * S + 3;
    constexpr int TX = 15 * S + 3;
    constexpr int NSLOT = ICC / 8;
    constexpr int SWMSK = NSLOT - 1;
    constexpr int KTOT = 9 * IC;
    __shared__ __align__(16) u16 sIn[TY * TX * ICC];

    const int tid  = threadIdx.x;
    const int lane = tid & 63;
    const int wid  = tid >> 6;
    const int wmi  = wid / NWN;
    const int wni  = wid % NWN;
    const int lm   = lane & 15;
    const int lk   = lane >> 4;

    f32x4 acc[FM][FN];
#pragma unroll
    for (int i = 0; i < FM; ++i)
#pragma unroll
        for (int j = 0; j < FN; ++j) acc[i][j] = (f32x4){0.f, 0.f, 0.f, 0.f};

    const int iy0 = blockIdx.y * 8 * S - 1;
    const int ix0 = blockIdx.x * 16 * S - 1;

    for (int c0 = 0; c0 < IC; c0 += ICC) {
        if (c0) __syncthreads();
        for (int u = tid; u < TY * TX * NSLOT; u += 256) {
            int yt = u / (TX * NSLOT);
            int r  = u - yt * (TX * NSLOT);
            int xt = r / NSLOT;
            int sl = r - xt * NSLOT;
            int gy = iy0 + yt; gy = gy < 0 ? -gy : (gy >= H ? 2 * H - 2 - gy : gy);
            int gx = ix0 + xt; gx = gx < 0 ? -gx : (gx >= W ? 2 * W - 2 - gx : gx);
            *(short8v*)((char*)sIn + (size_t)((yt * TX + xt) * NSLOT + (sl ^ (xt & SWMSK))) * 16) =
                *(const short8v*)(in + ((size_t)gy * W + gx) * IC + c0 + sl * 8);
        }
        __syncthreads();
#pragma unroll
        for (int tap = 0; tap < 9; ++tap) {
            const int dy = tap / 3, dx = tap % 3;
#pragma unroll
            for (int icw = 0; icw < ICC / 32; ++icw) {
                short8v a[FM], b[FN];
#pragma unroll
                for (int fm = 0; fm < FM; ++fm) {
                    int yt = (wmi * FM + fm) * S + dy;
                    int xt = lm * S + dx;
                    a[fm] = *(const short8v*)((const char*)sIn +
                        (size_t)((yt * TX + xt) * NSLOT + ((icw * 4 + lk) ^ (xt & SWMSK))) * 16);
                }
#pragma unroll
                for (int fn = 0; fn < FN; ++fn) {
                    int n = wni * FN * 16 + fn * 16 + lm;
                    b[fn] = *(const short8v*)(wgtP + (size_t)n * KTOT + tap * IC + c0 + icw * 32 + lk * 8);
                }
#pragma unroll
                for (int fm = 0; fm < FM; ++fm)
#pragma unroll
                    for (int fn = 0; fn < FN; ++fn)
                        acc[fm][fn] = __builtin_amdgcn_mfma_f32_16x16x32_bf16(
                            a[fm], b[fn], acc[fm][fn], 0, 0, 0);
            }
        }
    }

#pragma unroll
    for (int fm = 0; fm < FM; ++fm) {
        int y = blockIdx.y * 8 + wmi * FM + fm;
#pragma unroll
        for (int fn = 0; fn < FN; ++fn) {
            int oc = wni * FN * 16 + fn * 16 + lm;
            float bv = bias[oc];
#pragma unroll
            for (int i = 0; i < 4; ++i) {
                int x = blockIdx.x * 16 + lk * 4 + i;
                float v = acc[fm][fn][i] + bv;
                if (ACT == 0) v = v > 0.f ? v : 0.f;
                else          v = v > 0.f ? v : expm1f(v);
                size_t o = ((size_t)y * Wo + x) * OC + oc;
                if (OUTF32) ((float*)out)[o] = v;
                else        ((u16*)out)[o]   = f2bf(v);
            }
        }
    }
}

// channels-last f32 [36864][128] -> planar f32 [128][36864]
__global__ __launch_bounds__(256)
void cl2p_kernel(const float* __restrict__ in, float* __restrict__ out)
{
    __shared__ float t[32][130];
    const int tid = threadIdx.x;
    const int p0 = blockIdx.x * 32;
#pragma unroll
    for (int j = 0; j < 16; ++j) {
        int idx = j * 256 + tid;
        int px = idx >> 7, c = idx & 127;
        t[px][c] = in[(size_t)(p0 + px) * 128 + c];
    }
    __syncthreads();
#pragma unroll
    for (int j = 0; j < 16; ++j) {
        int c = j * 8 + (tid >> 5);
        int px = tid & 31;
        out[(size_t)c * 36864 + p0 + px] = t[px][c];
    }
}

// planar f32 [128][36864] -> channels-last bf16 [36864][128]
__global__ __launch_bounds__(256)
void p2cl_kernel(const float* __restrict__ in, u16* __restrict__ out)
{
    __shared__ float t[32][130];
    const int tid = threadIdx.x;
    const int p0 = blockIdx.x * 32;
#pragma unroll
    for (int j = 0; j < 16; ++j) {
        int c = j * 8 + (tid >> 5);
        int px = tid & 31;
        t[px][c] = in[(size_t)c * 36864 + p0 + px];
    }
    __syncthreads();
#pragma unroll
    for (int j = 0; j < 16; ++j) {
        int idx = j * 256 + tid;
        int px = idx >> 7, c = idx & 127;
        out[(size_t)(p0 + px) * 128 + c] = f2bf(t[px][c]);
    }
}

// ---------------- patch builders (h6 is channels-last bf16) -----------------
__global__ void build_patches_T(const u16* __restrict__ h6, const float* __restrict__ mask,
                                u16* __restrict__ fgpT, u16* __restrict__ bgpT)
{
    int idx = blockIdx.x * 256 + threadIdx.x;   // p*1152 + k
    if (idx >= 9216 * 1152) return;
    int p = idx / 1152, k = idx - p * 1152;
    int y = p / 96, x = p - y * 96;
    int c = k / 9, t = k - c * 9;
    int dy = t / 3, dx = t - dy * 3;
    int sy = y + dy - 1, sx = x + dx - 1;
    float v = 0.f, vm = 0.f;
    if (sy >= 0 && sy < 96 && sx >= 0 && sx < 96) {
        v  = bf2f(h6[((size_t)(2 * sy) * 192 + 2 * sx) * 128 + c]);
        vm = v * mask[(size_t)(2 * sy) * 192 + 2 * sx];
    }
    bgpT[idx] = f2bf(v);
    fgpT[idx] = f2bf(vm);
}

__global__ void build_patches_K(const u16* __restrict__ h6, const float* __restrict__ mask,
                                u16* __restrict__ fgpK, u16* __restrict__ bgpK)
{
    int idx = blockIdx.x * 256 + threadIdx.x;   // k*9216 + q
    if (idx >= 9216 * 1152) return;
    int k = idx / 9216, q = idx - k * 9216;
    int y = q / 96, x = q - y * 96;
    int c = k / 9, t = k - c * 9;
    int dy = t / 3, dx = t - dy * 3;
    int sy = y + dy - 1, sx = x + dx - 1;
    float v = 0.f, vm = 0.f;
    if (sy >= 0 && sy < 96 && sx >= 0 && sx < 96) {
        v  = bf2f(h6[((size_t)(2 * sy) * 192 + 2 * sx) * 128 + c]);
        vm = v * mask[(size_t)(2 * sy) * 192 + 2 * sx];
    }
    bgpK[idx] = f2bf(v);
    fgpK[idx] = f2bf(vm);
}

// ---------------- unified bf16 NT MFMA GEMM (attention) ---------------------
// D[m][n] = sum_k A[m][k]*B[n][k]; 128x128 tile, 4 waves, BK=64.
// Staging: global_load_lds w16, linear LDS dest, inverse-swizzled source.
// EPI: 1 = exp(scale*v)->bf16 + fused row-partials, 2 = fp32 +=, 3 = fp32 store
template<int EPI>
__global__ __launch_bounds__(256)
void mfma_nt_kernel(const u16* __restrict__ A, const u16* __restrict__ B,
                    int lda, int ldb, int K,
                    float* __restrict__ outF, u16* __restrict__ outH, int ldo,
                    const float* __restrict__ scale_p,
                    float* __restrict__ rsP, int rcol0)
{
    __shared__ __align__(16) u16 As[128 * 64];
    __shared__ __align__(16) u16 Bs[128 * 64];
    const int tid  = threadIdx.x;
    const int wid  = tid >> 6;
    const int lane = tid & 63;
    const int wm = (wid >> 1) * 64;
    const int wn = (wid & 1) * 64;
    const size_t bm = (size_t)blockIdx.y * 128;
    const size_t bn = (size_t)blockIdx.x * 128;

    f32x4 acc[4][4];
#pragma unroll
    for (int i = 0; i < 4; ++i)
#pragma unroll
        for (int j = 0; j < 4; ++j)
            acc[i][j] = (f32x4){0.f, 0.f, 0.f, 0.f};

    // staging geometry: wave wid owns rows [wid*32, wid*32+32) of As and Bs.
    // lane l -> row m0+(l>>3), global colbyte ((l&7)<<4) ^ ((l>>3 & 7)<<4)
    const int lrow = lane >> 3;
    const int lcb  = ((lane & 7) << 4) ^ ((lrow & 7) << 4);
    const char* gA = (const char*)A + ((bm + wid * 32 + lrow) * (size_t)lda) * 2 + lcb;
    const char* gB = (const char*)B + ((bn + wid * 32 + lrow) * (size_t)ldb) * 2 + lcb;
    char* lA = (char*)As + (size_t)(wid * 32) * 128;
    char* lB = (char*)Bs + (size_t)(wid * 32) * 128;
    const size_t rsA = (size_t)lda * 16;  // 8 rows, bytes
    const size_t rsB = (size_t)ldb * 16;

    for (int k0 = 0; k0 < K; k0 += 64) {
        __syncthreads();   // prev compute done reading LDS
#pragma unroll
        for (int j = 0; j < 4; ++j) {
            GLOAD16(gA + j * rsA + (size_t)k0 * 2, lA + j * 1024);
            GLOAD16(gB + j * rsB + (size_t)k0 * 2, lB + j * 1024);
        }
        __syncthreads();   // drains vmcnt(0): LDS ready
#pragma unroll
        for (int ks = 0; ks < 2; ++ks) {
            short8v a[4], b[4];
#pragma unroll
            for (int f = 0; f < 4; ++f) {
                int ma = wm + f * 16 + (lane & 15);
                int kba = (ks * 64 + ((lane >> 4) * 16)) ^ ((ma & 7) << 4);
                a[f] = *(const short8v*)((const char*)As + ma * 128 + kba);
                int nb = wn + f * 16 + (lane & 15);
                int kbb = (ks * 64 + ((lane >> 4) * 16)) ^ ((nb & 7) << 4);
                b[f] = *(const short8v*)((const char*)Bs + nb * 128 + kbb);
            }
#pragma unroll
            for (int fm = 0; fm < 4; ++fm)
#pragma unroll
                for (int fn = 0; fn < 4; ++fn)
                    acc[fm][fn] = __builtin_amdgcn_mfma_f32_16x16x32_bf16(
                        a[fm], b[fn], acc[fm][fn], 0, 0, 0);
        }
    }

    if (EPI == 1) {
        const float scale = *scale_p;
        float rloc[4][4];
#pragma unroll
        for (int fm = 0; fm < 4; ++fm)
#pragma unroll
            for (int i = 0; i < 4; ++i) rloc[fm][i] = 0.f;
#pragma unroll
        for (int fm = 0; fm < 4; ++fm)
#pragma unroll
            for (int fn = 0; fn < 4; ++fn)
#pragma unroll
                for (int i = 0; i < 4; ++i) {
                    int r = wm + fm * 16 + ((lane >> 4) * 4) + i;
                    int c = wn + fn * 16 + (lane & 15);
                    float e = __expf(scale * acc[fm][fn][i]);
                    outH[(bm + r) * (size_t)ldo + bn + c] = f2bf(e);
                    rloc[fm][i] += e;
                }
        // reduce over the 16 lanes holding different cols of the same rows
#pragma unroll
        for (int fm = 0; fm < 4; ++fm)
#pragma unroll
            for (int i = 0; i < 4; ++i) {
                float s = rloc[fm][i];
                s += __shfl_xor(s, 8, 64);
                s += __shfl_xor(s, 4, 64);
                s += __shfl_xor(s, 2, 64);
                s += __shfl_xor(s, 1, 64);
                if ((lane & 15) == 0)
                    rsP[(bm + wm + fm * 16 + ((lane >> 4) * 4) + i) * 144 +
                        rcol0 + blockIdx.x * 2 + (wid & 1)] = s;
            }
    } else {
#pragma unroll
        for (int fm = 0; fm < 4; ++fm)
#pragma unroll
            for (int fn = 0; fn < 4; ++fn)
#pragma unroll
                for (int i = 0; i < 4; ++i) {
                    int r = wm + fm * 16 + ((lane >> 4) * 4) + i;
                    int c = wn + fn * 16 + (lane & 15);
                    float v = acc[fm][fn][i];
                    if (EPI == 2) outF[(bm + r) * (size_t)ldo + bn + c] += v;
                    else          outF[(bm + r) * (size_t)ldo + bn + c]  = v;
                }
    }
}

// ---------------- Gram kernel: grid (9,9,8); z = pair*4 + splitK ------------
__global__ __launch_bounds__(256)
void gram_kernel(const u16* __restrict__ F, const u16* __restrict__ Bg,
                 float* __restrict__ GP)
{
    const u16* A = (blockIdx.z >> 2) ? Bg : F;
    const int split = blockIdx.z & 3;
    __shared__ __align__(16) u16 As[128 * 64];
    __shared__ __align__(16) u16 Bs[128 * 64];
    const int tid  = threadIdx.x;
    const int wid  = tid >> 6;
    const int lane = tid & 63;
    const int wm = (wid >> 1) * 64;
    const int wn = (wid & 1) * 64;
    const size_t bm = (size_t)blockIdx.y * 128;
    const size_t bn = (size_t)blockIdx.x * 128;

    f32x4 acc[4][4];
#pragma unroll
    for (int i = 0; i < 4; ++i)
#pragma unroll
        for (int j = 0; j < 4; ++j)
            acc[i][j] = (f32x4){0.f, 0.f, 0.f, 0.f};

    const int lrow = lane >> 3;
    const int lcb  = ((lane & 7) << 4) ^ ((lrow & 7) << 4);
    const char* gR = (const char*)A + ((bm + wid * 32 + lrow) * (size_t)9216) * 2 + lcb;
    const char* gC = (const char*)A + ((bn + wid * 32 + lrow) * (size_t)9216) * 2 + lcb;
    char* lA = (char*)As + (size_t)(wid * 32) * 128;
    char* lB = (char*)Bs + (size_t)(wid * 32) * 128;
    const size_t rs8 = (size_t)9216 * 16;
    const int kbeg = split * 2304;

    for (int k0 = kbeg; k0 < kbeg + 2304; k0 += 64) {
        __syncthreads();
#pragma unroll
        for (int j = 0; j < 4; ++j) {
            GLOAD16(gR + j * rs8 + (size_t)k0 * 2, lA + j * 1024);
            GLOAD16(gC + j * rs8 + (size_t)k0 * 2, lB + j * 1024);
        }
        __syncthreads();
#pragma unroll
        for (int ks = 0; ks < 2; ++ks) {
            short8v a[4], b[4];
#pragma unroll
            for (int f = 0; f < 4; ++f) {
                int ma = wm + f * 16 + (lane & 15);
                int kba = (ks * 64 + ((lane >> 4) * 16)) ^ ((ma & 7) << 4);
                a[f] = *(const short8v*)((const char*)As + ma * 128 + kba);
                int nb = wn + f * 16 + (lane & 15);
                int kbb = (ks * 64 + ((lane >> 4) * 16)) ^ ((nb & 7) << 4);
                b[f] = *(const short8v*)((const char*)Bs + nb * 128 + kbb);
            }
#pragma unroll
            for (int fm = 0; fm < 4; ++fm)
#pragma unroll
                for (int fn = 0; fn < 4; ++fn)
                    acc[fm][fn] = __builtin_amdgcn_mfma_f32_16x16x32_bf16(
                        a[fm], b[fn], acc[fm][fn], 0, 0, 0);
        }
    }

    float* out = GP + (size_t)blockIdx.z * 1327104;
#pragma unroll
    for (int fm = 0; fm < 4; ++fm)
#pragma unroll
        for (int fn = 0; fn < 4; ++fn)
#pragma unroll
            for (int i = 0; i < 4; ++i) {
                int r = wm + fm * 16 + ((lane >> 4) * 4) + i;
                int c = wn + fn * 16 + (lane & 15);
                out[(bm + r) * 1152 + bn + c] = acc[fm][fn][i];
            }
}

// dot over summed split-K partials: sum_i (sum_s GF_s[i]) * (sum_s GB_s[i])
__global__ void dot_gram_stage1(const float* __restrict__ GP, double* __restrict__ partial)
{
    const size_t n = 1327104;
    size_t i = (size_t)blockIdx.x * 256 + threadIdx.x;
    size_t stride = (size_t)gridDim.x * 256;
    double s = 0.0;
    for (; i < n; i += stride) {
        float gf = GP[i] + GP[n + i] + GP[2 * n + i] + GP[3 * n + i];
        float gb = GP[4 * n + i] + GP[5 * n + i] + GP[6 * n + i] + GP[7 * n + i];
        s += (double)gf * (double)gb;
    }
    for (int off = 32; off; off >>= 1) s += __shfl_down(s, off, 64);
    __shared__ double wsum[4];
    int lane = threadIdx.x & 63, wid = threadIdx.x >> 6;
    if (lane == 0) wsum[wid] = s;
    __syncthreads();
    if (threadIdx.x == 0) partial[blockIdx.x] = wsum[0] + wsum[1] + wsum[2] + wsum[3];
}

__global__ void sumsq_stage2(const double* __restrict__ partial, int nblocks, float* __restrict__ scale)
{
    double s = 0.0;
    for (int i = threadIdx.x; i < nblocks; i += 256) s += partial[i];
    for (int off = 32; off; off >>= 1) s += __shfl_down(s, off, 64);
    __shared__ double wsum[4];
    int lane = threadIdx.x & 63, wid = threadIdx.x >> 6;
    if (lane == 0) wsum[wid] = s;
    __syncthreads();
    if (threadIdx.x == 0) {
        double nrm = sqrt(wsum[0] + wsum[1] + wsum[2] + wsum[3]);
        if (nrm < 1e-12) nrm = 1e-12;
        *scale = (float)(10.0 / nrm);
    }
}

// inv[p] = 1 / sum_j rsP[p][j], fixed order (deterministic)
__global__ void inv_kernel(const float* __restrict__ rsP, float* __restrict__ inv)
{
    int i = blockIdx.x * 256 + threadIdx.x;
    if (i >= 9216) return;
    const float4* rp = (const float4*)(rsP + (size_t)i * 144);
    float s = 0.f;
#pragma unroll
    for (int j = 0; j < 36; ++j) {
        float4 v = rp[j];
        s += v.x + v.y + v.z + v.w;
    }
    inv[i] = 1.f / s;
}

// ---------------- fold + mask + upsample (planar fp32 out) ------------------
__global__ void fold_mask_up_kernel(const float* __restrict__ R2,
                                    const float* __restrict__ inv,
                                    const float* __restrict__ mask,
                                    float* __restrict__ up)
{
    int idx = blockIdx.x * 256 + threadIdx.x; // 128*96*96
    if (idx >= 128 * 96 * 96) return;
    int x = idx % 96;
    int y = (idx / 96) % 96;
    int c = idx / (96 * 96);
    float s = 0.f;
#pragma unroll
    for (int dy = 0; dy < 3; ++dy) {
        int yy = y + 1 - dy;
        if (yy < 0 || yy >= 96) continue;
#pragma unroll
        for (int dx = 0; dx < 3; ++dx) {
            int xx = x + 1 - dx;
            if (xx < 0 || xx >= 96) continue;
            int pp = yy * 96 + xx;
            s += R2[(size_t)(c * 9 + dy * 3 + dx) * 9216 + pp] * inv[pp];
        }
    }
    s *= mask[(size_t)(2 * y) * 192 + 2 * x];
    size_t base = (size_t)c * 192 * 192;
    up[base + (size_t)(2 * y) * 192 + 2 * x]         = s;
    up[base + (size_t)(2 * y) * 192 + 2 * x + 1]     = s;
    up[base + (size_t)(2 * y + 1) * 192 + 2 * x]     = s;
    up[base + (size_t)(2 * y + 1) * 192 + 2 * x + 1] = s;
}

// ---------------------------------------------------------------------------
extern "C" void kernel_launch(void* const* d_in, const int* in_sizes, int n_in,
                              void* d_out, int out_size, void* d_ws, size_t ws_size,
                              hipStream_t stream)
{
    const float* x    = (const float*)d_in[0];
    const float* mask = (const float*)d_in[1];
    const float* w[8];
    const float* b[8];
    for (int i = 0; i < 8; ++i) {
        w[i] = (const float*)d_in[2 + 2 * i];
        b[i] = (const float*)d_in[3 + 2 * i];
    }
    char* ws = (char*)d_ws;
    dim3 blk(256);

    // byte offsets (liveness-audited)
    const size_t U_H1CL = 0;            // cl bf16 768^2 x32  (37,748,736)
    const size_t U_H2   = 37748736;     // cl bf16 384^2 x32  ( 9,437,184)
    const size_t U_H3   = 47185920;     // cl bf16 384^2 x64  (18,874,368)
    const size_t U_H4   = 66060288;     // cl bf16 192^2 x128 ( 9,437,184)
    const size_t U_H5   = 75497472;
    const size_t U_H6   = 84934656;     // ends 94,371,840
    const size_t U_FGPT = 0;            // 21,233,664 each (over dead h1cl..h5)
    const size_t U_BGPT = 21233664;
    const size_t U_FGPK = 42467328;
    const size_t U_BGPK = 63700992;     // ends 84,934,656 (== h6 start)
    const size_t F_GP   = 84934656;     // 8 x 1152^2 fp32 = 42,467,328 (over dead h6)
    const size_t F_R2   = 84934656;     // fp32 [1152][9216] (after GP dead)
    const size_t U_P    = 127401984;    // bf16 9216x1536 (28,311,552) -> 155,713,536
    const size_t F_RSP  = 155713536;    // fp32 9216x144 (5,308,416) -> 161,021,952
    const size_t F_INV2 = 161021952;    //  36,864 -> 161,058,816
    const size_t F_UP   = 0;            // planar fp32 128x192^2 (18,874,368)
    const size_t U_UPCL = 18874368;     // cl bf16 ( 9,437,184)
    const size_t U_H7   = 28311552;     // cl bf16
    const size_t F_H8   = 37748736;     // cl fp32 (18,874,368) -> 56,623,104
    const size_t U_WP2  = 178000000;    //  18,432
    const size_t U_WP3  = 178018432;    //  36,864
    const size_t U_WP4  = 178055296;    // 147,456
    const size_t U_WP5  = 178202752;    // 294,912
    const size_t U_WP6  = 178497664;
    const size_t U_WP7  = 178792576;
    const size_t U_WP8  = 179087488;    // ends 179,382,400
    const size_t D_RED  = 179382400;    //   4,096
    const size_t F_SCALE= 179386496;    // ends ~179,386,752 (peak 179.46 MB)

    u16* h1cl   = (u16*)(ws + U_H1CL);
    u16* h2     = (u16*)(ws + U_H2);
    u16* h3     = (u16*)(ws + U_H3);
    u16* h4     = (u16*)(ws + U_H4);
    u16* h5     = (u16*)(ws + U_H5);
    u16* h6     = (u16*)(ws + U_H6);
    u16* fgpT   = (u16*)(ws + U_FGPT);
    u16* bgpT   = (u16*)(ws + U_BGPT);
    u16* fgpK   = (u16*)(ws + U_FGPK);
    u16* bgpK   = (u16*)(ws + U_BGPK);
    float* GP   = (float*)(ws + F_GP);
    float* R2   = (float*)(ws + F_R2);
    u16* P      = (u16*)(ws + U_P);
    float* rsP  = (float*)(ws + F_RSP);
    float* inv  = (float*)(ws + F_INV2);
    float* upP  = (float*)(ws + F_UP);
    u16* upCL   = (u16*)(ws + U_UPCL);
    u16* h7     = (u16*)(ws + U_H7);
    float* h8   = (float*)(ws + F_H8);
    u16* wp2    = (u16*)(ws + U_WP2);
    u16* wp3    = (u16*)(ws + U_WP3);
    u16* wp4    = (u16*)(ws + U_WP4);
    u16* wp5    = (u16*)(ws + U_WP5);
    u16* wp6    = (u16*)(ws + U_WP6);
    u16* wp7    = (u16*)(ws + U_WP7);
    u16* wp8    = (u16*)(ws + U_WP8);
    double* red = (double*)(ws + D_RED);
    float* scale= (float*)(ws + F_SCALE);

    // ---- weight prepack ----
    pack_w_kernel<<<dim3(36),  blk, 0, stream>>>(w[1], wp2, 32, 32);
    pack_w_kernel<<<dim3(72),  blk, 0, stream>>>(w[2], wp3, 64, 32);
    pack_w_kernel<<<dim3(288), blk, 0, stream>>>(w[3], wp4, 128, 64);
    pack_w_kernel<<<dim3(576), blk, 0, stream>>>(w[4], wp5, 128, 128);
    pack_w_kernel<<<dim3(576), blk, 0, stream>>>(w[5], wp6, 128, 128);
    pack_w_kernel<<<dim3(576), blk, 0, stream>>>(w[6], wp7, 128, 128);
    pack_w_kernel<<<dim3(576), blk, 0, stream>>>(w[7], wp8, 128, 128);

    // ---- conv front-end ----
    conv1_kernel<<<dim3(48, 48), blk, 0, stream>>>(x, w[0], b[0], h1cl);
    mfma_conv_kernel<4, 1, 2, 2, 2, 32, 32, 1, 0><<<dim3(24, 48), blk, 0, stream>>>(
        h1cl, wp2, b[1], h2, 768, 768, 384, 384, 32);
    mfma_conv_kernel<4, 2, 2, 2, 1, 32, 32, 1, 0><<<dim3(24, 48), blk, 0, stream>>>(
        h2, wp3, b[2], h3, 384, 384, 384, 384, 64);
    mfma_conv_kernel<4, 4, 2, 2, 2, 64, 32, 1, 0><<<dim3(12, 24), blk, 0, stream>>>(
        h3, wp4, b[3], h4, 384, 384, 192, 192, 128);
    mfma_conv_kernel<4, 4, 2, 2, 1, 128, 128, 1, 0><<<dim3(12, 24), blk, 0, stream>>>(
        h4, wp5, b[4], h5, 192, 192, 192, 192, 128);
    mfma_conv_kernel<4, 4, 2, 2, 1, 128, 128, 0, 0><<<dim3(12, 24), blk, 0, stream>>>(
        h5, wp6, b[5], h6, 192, 192, 192, 192, 128);

    // ---- patch matrices ----
    build_patches_T<<<dim3(41472), blk, 0, stream>>>(h6, mask, fgpT, bgpT);
    build_patches_K<<<dim3(41472), blk, 0, stream>>>(h6, mask, fgpK, bgpK);

    // ---- norm scale via Gram trick (merged fg/bg + split-K, 648 blocks) ----
    gram_kernel<<<dim3(9, 9, 8), blk, 0, stream>>>(fgpK, bgpK, GP);
    dot_gram_stage1<<<dim3(512), blk, 0, stream>>>(GP, red);
    sumsq_stage2<<<dim3(1), blk, 0, stream>>>(red, 512, scale);

    // ---- 6 q-stripes: S-exp (fused row-partials) -> P, PV accumulate ----
    for (int s = 0; s < 6; ++s) {
        size_t qs = (size_t)s * 1536;
        mfma_nt_kernel<1><<<dim3(12, 72), blk, 0, stream>>>(
            fgpT, bgpT + qs * 1152, 1152, 1152, 1152, nullptr, P, 1536, scale,
            rsP, s * 24);
        if (s == 0)
            mfma_nt_kernel<3><<<dim3(72, 9), blk, 0, stream>>>(
                bgpK + qs, P, 9216, 1536, 1536, R2, nullptr, 9216, nullptr, nullptr, 0);
        else
            mfma_nt_kernel<2><<<dim3(72, 9), blk, 0, stream>>>(
                bgpK + qs, P, 9216, 1536, 1536, R2, nullptr, 9216, nullptr, nullptr, 0);
    }
    inv_kernel<<<dim3(36), blk, 0, stream>>>(rsP, inv);
    fold_mask_up_kernel<<<dim3(4608), blk, 0, stream>>>(R2, inv, mask, upP);

    // ---- back-end convs ----
    p2cl_kernel<<<dim3(1152), blk, 0, stream>>>(upP, upCL);
    mfma_conv_kernel<4, 4, 2, 2, 1, 128, 128, 1, 0><<<dim3(12, 24), blk, 0, stream>>>(
        upCL, wp7, b[6], h7, 192, 192, 192, 192, 128);
    mfma_conv_kernel<4, 4, 2, 2, 1, 128, 128, 1, 1><<<dim3(12, 24), blk, 0, stream>>>(
        h7, wp8, b[7], h8, 192, 192, 192, 192, 128);
    cl2p_kernel<<<dim3(1152), blk, 0, stream>>>(h8, (float*)d_out);
}

// Round 7
// 973.847 us; speedup vs baseline: 13.6946x; 1.2364x over previous
//
#include <hip/hip_runtime.h>
#include <math.h>

// ---------------------------------------------------------------------------
// Round 6->7: conv1 -> MFMA implicit GEMM (K=128: 32 taps x 4 padded ch),
// OC z-split for conv4..8 (576-block grids), 3 q-stripes of 3072.
// Workspace peak ~169.5 MB (< 180.56 MB proven safe).
// ---------------------------------------------------------------------------

typedef unsigned short u16;
typedef short short4v __attribute__((ext_vector_type(4)));
typedef short short8v __attribute__((ext_vector_type(8)));
typedef float f32x4 __attribute__((ext_vector_type(4)));

__device__ __forceinline__ u16 f2bf(float f) {
    unsigned u = __float_as_uint(f);
    return (u16)((u + 0x7FFF + ((u >> 16) & 1)) >> 16);
}
__device__ __forceinline__ float bf2f(u16 h) {
    return __uint_as_float(((unsigned)h) << 16);
}

#define GLOAD16(g, l) __builtin_amdgcn_global_load_lds(                      \
    (const __attribute__((address_space(1))) void*)(g),                      \
    (__attribute__((address_space(3))) void*)(l), 16, 0, 0)

// ---------------- x -> channels-last bf16 ic4 (for conv1 MFMA) --------------
__global__ void x4cl_kernel(const float* __restrict__ x, u16* __restrict__ out)
{
    int i = blockIdx.x * 256 + threadIdx.x;   // 589824 pixels
    if (i >= 589824) return;
    u16 v[4];
    v[0] = f2bf(x[i]);
    v[1] = f2bf(x[589824 + i]);
    v[2] = f2bf(x[1179648 + i]);
    v[3] = 0;
    *(short4v*)(out + (size_t)i * 4) = *(short4v*)v;
}

// w1 [32][3][5][5] f32 -> wp1 [32][128] bf16, k = tap*4+ic (pad zeros)
__global__ void pack_w1_kernel(const float* __restrict__ w, u16* __restrict__ wp)
{
    int i = blockIdx.x * 256 + threadIdx.x;   // 4096
    if (i >= 4096) return;
    int oc = i >> 7, k = i & 127;
    int tap = k >> 2, ic = k & 3;
    u16 v = 0;
    if (tap < 25 && ic < 3) v = f2bf(w[oc * 75 + ic * 25 + tap]);
    wp[i] = v;
}

// ---------------- conv1 MFMA: 3->32, 5x5, s1, reflect pad2, ELU -------------
// M = 128 pixels (8y x 16x), N = 32 oc, K = 128 (32 taps x 4 ic, zero-padded)
__global__ __launch_bounds__(256)
void conv1_mfma_kernel(const u16* __restrict__ x4, const u16* __restrict__ wp1,
                       const float* __restrict__ bias, u16* __restrict__ out)
{
    __shared__ __align__(16) u16 sIn[12 * 20 * 4];   // [yt][xt][ic4]
    const int tid = threadIdx.x;
    const int lane = tid & 63;
    const int w = tid >> 6;
    const int lm = lane & 15;
    const int lk = lane >> 4;
    const int oy0 = blockIdx.y * 8, ox0 = blockIdx.x * 16;

    for (int u = tid; u < 240; u += 256) {
        int yt = u / 20, xt = u - yt * 20;
        int gy = oy0 - 2 + yt; gy = gy < 0 ? -gy : (gy >= 768 ? 1534 - gy : gy);
        int gx = ox0 - 2 + xt; gx = gx < 0 ? -gx : (gx >= 768 ? 1534 - gx : gx);
        *(short4v*)(sIn + u * 4) = *(const short4v*)(x4 + ((size_t)gy * 768 + gx) * 4);
    }
    // per-lane tap offsets: K-step ks covers taps [8ks, 8ks+8); lane's 2 taps
    int aoff[4][2];
#pragma unroll
    for (int ks = 0; ks < 4; ++ks) {
        int t0 = ks * 8 + lk * 2;
        int t1 = t0 + 1;
        if (t0 > 24) t0 = 24;
        if (t1 > 24) t1 = 24;
        int dy0 = t0 / 5, dx0 = t0 - 5 * dy0;
        int dy1 = t1 / 5, dx1 = t1 - 5 * dy1;
        aoff[ks][0] = (dy0 * 20 + dx0 + lm) * 4;
        aoff[ks][1] = (dy1 * 20 + dx1 + lm) * 4;
    }
    __syncthreads();

    f32x4 acc[2][2];
#pragma unroll
    for (int i = 0; i < 2; ++i)
#pragma unroll
        for (int j = 0; j < 2; ++j) acc[i][j] = (f32x4){0.f, 0.f, 0.f, 0.f};

#pragma unroll
    for (int ks = 0; ks < 4; ++ks) {
        short8v a[2], b[2];
#pragma unroll
        for (int fm = 0; fm < 2; ++fm) {
            int base = (w * 2 + fm) * 80;   // yy * 20 pixels * 4 elems
            short4v lo = *(const short4v*)(sIn + base + aoff[ks][0]);
            short4v hi = *(const short4v*)(sIn + base + aoff[ks][1]);
            short8v av;
            av[0] = lo[0]; av[1] = lo[1]; av[2] = lo[2]; av[3] = lo[3];
            av[4] = hi[0]; av[5] = hi[1]; av[6] = hi[2]; av[7] = hi[3];
            a[fm] = av;
        }
#pragma unroll
        for (int fn = 0; fn < 2; ++fn)
            b[fn] = *(const short8v*)(wp1 + (size_t)(fn * 16 + lm) * 128 + ks * 32 + lk * 8);
#pragma unroll
        for (int fm = 0; fm < 2; ++fm)
#pragma unroll
            for (int fn = 0; fn < 2; ++fn)
                acc[fm][fn] = __builtin_amdgcn_mfma_f32_16x16x32_bf16(
                    a[fm], b[fn], acc[fm][fn], 0, 0, 0);
    }

#pragma unroll
    for (int fm = 0; fm < 2; ++fm) {
        int gy = oy0 + w * 2 + fm;
#pragma unroll
        for (int fn = 0; fn < 2; ++fn) {
            int oc = fn * 16 + lm;
            float bv = bias[oc];
#pragma unroll
            for (int i = 0; i < 4; ++i) {
                int xx = lk * 4 + i;
                float v = acc[fm][fn][i] + bv;
                v = v > 0.f ? v : expm1f(v);
                out[((size_t)gy * 768 + ox0 + xx) * 32 + oc] = f2bf(v);
            }
        }
    }
}

// ---------------- weight prepack: [oc][ic][3][3] f32 -> [oc][tap][ic] bf16 --
__global__ void pack_w_kernel(const float* __restrict__ w, u16* __restrict__ wp,
                              int OC, int IC)
{
    int idx = blockIdx.x * 256 + threadIdx.x;
    if (idx >= OC * 9 * IC) return;
    int oc = idx / (9 * IC);
    int r  = idx - oc * 9 * IC;
    int tap = r / IC;
    int ic  = r - tap * IC;
    wp[idx] = f2bf(w[((size_t)oc * IC + ic) * 9 + tap]);
}

// ---------------- MFMA implicit-GEMM conv (3x3, reflect pad 1) --------------
// OC covered per block = NWN*FN*16, offset by blockIdx.z * that.
template<int FM, int FN, int NWM, int NWN, int S, int IC, int ICC, int ACT, int OUTF32>
__global__ __launch_bounds__(256)
void mfma_conv_kernel(const u16* __restrict__ in, const u16* __restrict__ wgtP,
                      const float* __restrict__ bias, void* __restrict__ out,
                      int H, int W, int Ho, int Wo, int OC)
{
    constexpr int TY = 7 * S + 3;
    constexpr int TX = 15 * S + 3;
    constexpr int NSLOT = ICC / 8;
    constexpr int SWMSK = NSLOT - 1;
    constexpr int KTOT = 9 * IC;
    __shared__ __align__(16) u16 sIn[TY * TX * ICC];

    const int tid  = threadIdx.x;
    const int lane = tid & 63;
    const int wid  = tid >> 6;
    const int wmi  = wid / NWN;
    const int wni  = wid % NWN;
    const int lm   = lane & 15;
    const int lk   = lane >> 4;
    const int noff = blockIdx.z * (NWN * FN * 16);

    f32x4 acc[FM][FN];
#pragma unroll
    for (int i = 0; i < FM; ++i)
#pragma unroll
        for (int j = 0; j < FN; ++j) acc[i][j] = (f32x4){0.f, 0.f, 0.f, 0.f};

    const int iy0 = blockIdx.y * 8 * S - 1;
    const int ix0 = blockIdx.x * 16 * S - 1;

    for (int c0 = 0; c0 < IC; c0 += ICC) {
        if (c0) __syncthreads();
        for (int u = tid; u < TY * TX * NSLOT; u += 256) {
            int yt = u / (TX * NSLOT);
            int r  = u - yt * (TX * NSLOT);
            int xt = r / NSLOT;
            int sl = r - xt * NSLOT;
            int gy = iy0 + yt; gy = gy < 0 ? -gy : (gy >= H ? 2 * H - 2 - gy : gy);
            int gx = ix0 + xt; gx = gx < 0 ? -gx : (gx >= W ? 2 * W - 2 - gx : gx);
            *(short8v*)((char*)sIn + (size_t)((yt * TX + xt) * NSLOT + (sl ^ (xt & SWMSK))) * 16) =
                *(const short8v*)(in + ((size_t)gy * W + gx) * IC + c0 + sl * 8);
        }
        __syncthreads();
#pragma unroll
        for (int tap = 0; tap < 9; ++tap) {
            const int dy = tap / 3, dx = tap % 3;
#pragma unroll
            for (int icw = 0; icw < ICC / 32; ++icw) {
                short8v a[FM], b[FN];
#pragma unroll
                for (int fm = 0; fm < FM; ++fm) {
                    int yt = (wmi * FM + fm) * S + dy;
                    int xt = lm * S + dx;
                    a[fm] = *(const short8v*)((const char*)sIn +
                        (size_t)((yt * TX + xt) * NSLOT + ((icw * 4 + lk) ^ (xt & SWMSK))) * 16);
                }
#pragma unroll
                for (int fn = 0; fn < FN; ++fn) {
                    int n = noff + wni * FN * 16 + fn * 16 + lm;
                    b[fn] = *(const short8v*)(wgtP + (size_t)n * KTOT + tap * IC + c0 + icw * 32 + lk * 8);
                }
#pragma unroll
                for (int fm = 0; fm < FM; ++fm)
#pragma unroll
                    for (int fn = 0; fn < FN; ++fn)
                        acc[fm][fn] = __builtin_amdgcn_mfma_f32_16x16x32_bf16(
                            a[fm], b[fn], acc[fm][fn], 0, 0, 0);
            }
        }
    }

#pragma unroll
    for (int fm = 0; fm < FM; ++fm) {
        int y = blockIdx.y * 8 + wmi * FM + fm;
#pragma unroll
        for (int fn = 0; fn < FN; ++fn) {
            int oc = noff + wni * FN * 16 + fn * 16 + lm;
            float bv = bias[oc];
#pragma unroll
            for (int i = 0; i < 4; ++i) {
                int x = blockIdx.x * 16 + lk * 4 + i;
                float v = acc[fm][fn][i] + bv;
                if (ACT == 0) v = v > 0.f ? v : 0.f;
                else          v = v > 0.f ? v : expm1f(v);
                size_t o = ((size_t)y * Wo + x) * OC + oc;
                if (OUTF32) ((float*)out)[o] = v;
                else        ((u16*)out)[o]   = f2bf(v);
            }
        }
    }
}

// channels-last f32 [36864][128] -> planar f32 [128][36864]
__global__ __launch_bounds__(256)
void cl2p_kernel(const float* __restrict__ in, float* __restrict__ out)
{
    __shared__ float t[32][130];
    const int tid = threadIdx.x;
    const int p0 = blockIdx.x * 32;
#pragma unroll
    for (int j = 0; j < 16; ++j) {
        int idx = j * 256 + tid;
        int px = idx >> 7, c = idx & 127;
        t[px][c] = in[(size_t)(p0 + px) * 128 + c];
    }
    __syncthreads();
#pragma unroll
    for (int j = 0; j < 16; ++j) {
        int c = j * 8 + (tid >> 5);
        int px = tid & 31;
        out[(size_t)c * 36864 + p0 + px] = t[px][c];
    }
}

// planar f32 [128][36864] -> channels-last bf16 [36864][128]
__global__ __launch_bounds__(256)
void p2cl_kernel(const float* __restrict__ in, u16* __restrict__ out)
{
    __shared__ float t[32][130];
    const int tid = threadIdx.x;
    const int p0 = blockIdx.x * 32;
#pragma unroll
    for (int j = 0; j < 16; ++j) {
        int c = j * 8 + (tid >> 5);
        int px = tid & 31;
        t[px][c] = in[(size_t)c * 36864 + p0 + px];
    }
    __syncthreads();
#pragma unroll
    for (int j = 0; j < 16; ++j) {
        int idx = j * 256 + tid;
        int px = idx >> 7, c = idx & 127;
        out[(size_t)(p0 + px) * 128 + c] = f2bf(t[px][c]);
    }
}

// ---------------- patch builders (h6 is channels-last bf16) -----------------
__global__ void build_patches_T(const u16* __restrict__ h6, const float* __restrict__ mask,
                                u16* __restrict__ fgpT, u16* __restrict__ bgpT)
{
    int idx = blockIdx.x * 256 + threadIdx.x;   // p*1152 + k
    if (idx >= 9216 * 1152) return;
    int p = idx / 1152, k = idx - p * 1152;
    int y = p / 96, x = p - y * 96;
    int c = k / 9, t = k - c * 9;
    int dy = t / 3, dx = t - dy * 3;
    int sy = y + dy - 1, sx = x + dx - 1;
    float v = 0.f, vm = 0.f;
    if (sy >= 0 && sy < 96 && sx >= 0 && sx < 96) {
        v  = bf2f(h6[((size_t)(2 * sy) * 192 + 2 * sx) * 128 + c]);
        vm = v * mask[(size_t)(2 * sy) * 192 + 2 * sx];
    }
    bgpT[idx] = f2bf(v);
    fgpT[idx] = f2bf(vm);
}

__global__ void build_patches_K(const u16* __restrict__ h6, const float* __restrict__ mask,
                                u16* __restrict__ fgpK, u16* __restrict__ bgpK)
{
    int idx = blockIdx.x * 256 + threadIdx.x;   // k*9216 + q
    if (idx >= 9216 * 1152) return;
    int k = idx / 9216, q = idx - k * 9216;
    int y = q / 96, x = q - y * 96;
    int c = k / 9, t = k - c * 9;
    int dy = t / 3, dx = t - dy * 3;
    int sy = y + dy - 1, sx = x + dx - 1;
    float v = 0.f, vm = 0.f;
    if (sy >= 0 && sy < 96 && sx >= 0 && sx < 96) {
        v  = bf2f(h6[((size_t)(2 * sy) * 192 + 2 * sx) * 128 + c]);
        vm = v * mask[(size_t)(2 * sy) * 192 + 2 * sx];
    }
    bgpK[idx] = f2bf(v);
    fgpK[idx] = f2bf(vm);
}

// ---------------- unified bf16 NT MFMA GEMM (attention) ---------------------
// EPI: 1 = exp(scale*v)->bf16 + fused row-partials, 2 = fp32 +=, 3 = fp32 store
template<int EPI>
__global__ __launch_bounds__(256)
void mfma_nt_kernel(const u16* __restrict__ A, const u16* __restrict__ B,
                    int lda, int ldb, int K,
                    float* __restrict__ outF, u16* __restrict__ outH, int ldo,
                    const float* __restrict__ scale_p,
                    float* __restrict__ rsP, int rcol0)
{
    __shared__ __align__(16) u16 As[128 * 64];
    __shared__ __align__(16) u16 Bs[128 * 64];
    const int tid  = threadIdx.x;
    const int wid  = tid >> 6;
    const int lane = tid & 63;
    const int wm = (wid >> 1) * 64;
    const int wn = (wid & 1) * 64;
    const size_t bm = (size_t)blockIdx.y * 128;
    const size_t bn = (size_t)blockIdx.x * 128;

    f32x4 acc[4][4];
#pragma unroll
    for (int i = 0; i < 4; ++i)
#pragma unroll
        for (int j = 0; j < 4; ++j)
            acc[i][j] = (f32x4){0.f, 0.f, 0.f, 0.f};

    const int lrow = lane >> 3;
    const int lcb  = ((lane & 7) << 4) ^ ((lrow & 7) << 4);
    const char* gA = (const char*)A + ((bm + wid * 32 + lrow) * (size_t)lda) * 2 + lcb;
    const char* gB = (const char*)B + ((bn + wid * 32 + lrow) * (size_t)ldb) * 2 + lcb;
    char* lA = (char*)As + (size_t)(wid * 32) * 128;
    char* lB = (char*)Bs + (size_t)(wid * 32) * 128;
    const size_t rsA = (size_t)lda * 16;
    const size_t rsB = (size_t)ldb * 16;

    for (int k0 = 0; k0 < K; k0 += 64) {
        __syncthreads();
#pragma unroll
        for (int j = 0; j < 4; ++j) {
            GLOAD16(gA + j * rsA + (size_t)k0 * 2, lA + j * 1024);
            GLOAD16(gB + j * rsB + (size_t)k0 * 2, lB + j * 1024);
        }
        __syncthreads();
#pragma unroll
        for (int ks = 0; ks < 2; ++ks) {
            short8v a[4], b[4];
#pragma unroll
            for (int f = 0; f < 4; ++f) {
                int ma = wm + f * 16 + (lane & 15);
                int kba = (ks * 64 + ((lane >> 4) * 16)) ^ ((ma & 7) << 4);
                a[f] = *(const short8v*)((const char*)As + ma * 128 + kba);
                int nb = wn + f * 16 + (lane & 15);
                int kbb = (ks * 64 + ((lane >> 4) * 16)) ^ ((nb & 7) << 4);
                b[f] = *(const short8v*)((const char*)Bs + nb * 128 + kbb);
            }
#pragma unroll
            for (int fm = 0; fm < 4; ++fm)
#pragma unroll
                for (int fn = 0; fn < 4; ++fn)
                    acc[fm][fn] = __builtin_amdgcn_mfma_f32_16x16x32_bf16(
                        a[fm], b[fn], acc[fm][fn], 0, 0, 0);
        }
    }

    if (EPI == 1) {
        const float scale = *scale_p;
        float rloc[4][4];
#pragma unroll
        for (int fm = 0; fm < 4; ++fm)
#pragma unroll
            for (int i = 0; i < 4; ++i) rloc[fm][i] = 0.f;
#pragma unroll
        for (int fm = 0; fm < 4; ++fm)
#pragma unroll
            for (int fn = 0; fn < 4; ++fn)
#pragma unroll
                for (int i = 0; i < 4; ++i) {
                    int r = wm + fm * 16 + ((lane >> 4) * 4) + i;
                    int c = wn + fn * 16 + (lane & 15);
                    float e = __expf(scale * acc[fm][fn][i]);
                    outH[(bm + r) * (size_t)ldo + bn + c] = f2bf(e);
                    rloc[fm][i] += e;
                }
#pragma unroll
        for (int fm = 0; fm < 4; ++fm)
#pragma unroll
            for (int i = 0; i < 4; ++i) {
                float s = rloc[fm][i];
                s += __shfl_xor(s, 8, 64);
                s += __shfl_xor(s, 4, 64);
                s += __shfl_xor(s, 2, 64);
                s += __shfl_xor(s, 1, 64);
                if ((lane & 15) == 0)
                    rsP[(bm + wm + fm * 16 + ((lane >> 4) * 4) + i) * 144 +
                        rcol0 + blockIdx.x * 2 + (wid & 1)] = s;
            }
    } else {
#pragma unroll
        for (int fm = 0; fm < 4; ++fm)
#pragma unroll
            for (int fn = 0; fn < 4; ++fn)
#pragma unroll
                for (int i = 0; i < 4; ++i) {
                    int r = wm + fm * 16 + ((lane >> 4) * 4) + i;
                    int c = wn + fn * 16 + (lane & 15);
                    float v = acc[fm][fn][i];
                    if (EPI == 2) outF[(bm + r) * (size_t)ldo + bn + c] += v;
                    else          outF[(bm + r) * (size_t)ldo + bn + c]  = v;
                }
    }
}

// ---------------- Gram kernel: grid (9,9,8); z = pair*4 + splitK ------------
__global__ __launch_bounds__(256)
void gram_kernel(const u16* __restrict__ F, const u16* __restrict__ Bg,
                 float* __restrict__ GP)
{
    const u16* A = (blockIdx.z >> 2) ? Bg : F;
    const int split = blockIdx.z & 3;
    __shared__ __align__(16) u16 As[128 * 64];
    __shared__ __align__(16) u16 Bs[128 * 64];
    const int tid  = threadIdx.x;
    const int wid  = tid >> 6;
    const int lane = tid & 63;
    const int wm = (wid >> 1) * 64;
    const int wn = (wid & 1) * 64;
    const size_t bm = (size_t)blockIdx.y * 128;
    const size_t bn = (size_t)blockIdx.x * 128;

    f32x4 acc[4][4];
#pragma unroll
    for (int i = 0; i < 4; ++i)
#pragma unroll
        for (int j = 0; j < 4; ++j)
            acc[i][j] = (f32x4){0.f, 0.f, 0.f, 0.f};

    const int lrow = lane >> 3;
    const int lcb  = ((lane & 7) << 4) ^ ((lrow & 7) << 4);
    const char* gR = (const char*)A + ((bm + wid * 32 + lrow) * (size_t)9216) * 2 + lcb;
    const char* gC = (const char*)A + ((bn + wid * 32 + lrow) * (size_t)9216) * 2 + lcb;
    char* lA = (char*)As + (size_t)(wid * 32) * 128;
    char* lB = (char*)Bs + (size_t)(wid * 32) * 128;
    const size_t rs8 = (size_t)9216 * 16;
    const int kbeg = split * 2304;

    for (int k0 = kbeg; k0 < kbeg + 2304; k0 += 64) {
        __syncthreads();
#pragma unroll
        for (int j = 0; j < 4; ++j) {
            GLOAD16(gR + j * rs8 + (size_t)k0 * 2, lA + j * 1024);
            GLOAD16(gC + j * rs8 + (size_t)k0 * 2, lB + j * 1024);
        }
        __syncthreads();
#pragma unroll
        for (int ks = 0; ks < 2; ++ks) {
            short8v a[4], b[4];
#pragma unroll
            for (int f = 0; f < 4; ++f) {
                int ma = wm + f * 16 + (lane & 15);
                int kba = (ks * 64 + ((lane >> 4) * 16)) ^ ((ma & 7) << 4);
                a[f] = *(const short8v*)((const char*)As + ma * 128 + kba);
                int nb = wn + f * 16 + (lane & 15);
                int kbb = (ks * 64 + ((lane >> 4) * 16)) ^ ((nb & 7) << 4);
                b[f] = *(const short8v*)((const char*)Bs + nb * 128 + kbb);
            }
#pragma unroll
            for (int fm = 0; fm < 4; ++fm)
#pragma unroll
                for (int fn = 0; fn < 4; ++fn)
                    acc[fm][fn] = __builtin_amdgcn_mfma_f32_16x16x32_bf16(
                        a[fm], b[fn], acc[fm][fn], 0, 0, 0);
        }
    }

    float* out = GP + (size_t)blockIdx.z * 1327104;
#pragma unroll
    for (int fm = 0; fm < 4; ++fm)
#pragma unroll
        for (int fn = 0; fn < 4; ++fn)
#pragma unroll
            for (int i = 0; i < 4; ++i) {
                int r = wm + fm * 16 + ((lane >> 4) * 4) + i;
                int c = wn + fn * 16 + (lane & 15);
                out[(bm + r) * 1152 + bn + c] = acc[fm][fn][i];
            }
}

__global__ void dot_gram_stage1(const float* __restrict__ GP, double* __restrict__ partial)
{
    const size_t n = 1327104;
    size_t i = (size_t)blockIdx.x * 256 + threadIdx.x;
    size_t stride = (size_t)gridDim.x * 256;
    double s = 0.0;
    for (; i < n; i += stride) {
        float gf = GP[i] + GP[n + i] + GP[2 * n + i] + GP[3 * n + i];
        float gb = GP[4 * n + i] + GP[5 * n + i] + GP[6 * n + i] + GP[7 * n + i];
        s += (double)gf * (double)gb;
    }
    for (int off = 32; off; off >>= 1) s += __shfl_down(s, off, 64);
    __shared__ double wsum[4];
    int lane = threadIdx.x & 63, wid = threadIdx.x >> 6;
    if (lane == 0) wsum[wid] = s;
    __syncthreads();
    if (threadIdx.x == 0) partial[blockIdx.x] = wsum[0] + wsum[1] + wsum[2] + wsum[3];
}

__global__ void sumsq_stage2(const double* __restrict__ partial, int nblocks, float* __restrict__ scale)
{
    double s = 0.0;
    for (int i = threadIdx.x; i < nblocks; i += 256) s += partial[i];
    for (int off = 32; off; off >>= 1) s += __shfl_down(s, off, 64);
    __shared__ double wsum[4];
    int lane = threadIdx.x & 63, wid = threadIdx.x >> 6;
    if (lane == 0) wsum[wid] = s;
    __syncthreads();
    if (threadIdx.x == 0) {
        double nrm = sqrt(wsum[0] + wsum[1] + wsum[2] + wsum[3]);
        if (nrm < 1e-12) nrm = 1e-12;
        *scale = (float)(10.0 / nrm);
    }
}

__global__ void inv_kernel(const float* __restrict__ rsP, float* __restrict__ inv)
{
    int i = blockIdx.x * 256 + threadIdx.x;
    if (i >= 9216) return;
    const float4* rp = (const float4*)(rsP + (size_t)i * 144);
    float s = 0.f;
#pragma unroll
    for (int j = 0; j < 36; ++j) {
        float4 v = rp[j];
        s += v.x + v.y + v.z + v.w;
    }
    inv[i] = 1.f / s;
}

// ---------------- fold + mask + upsample (planar fp32 out) ------------------
__global__ void fold_mask_up_kernel(const float* __restrict__ R2,
                                    const float* __restrict__ inv,
                                    const float* __restrict__ mask,
                                    float* __restrict__ up)
{
    int idx = blockIdx.x * 256 + threadIdx.x; // 128*96*96
    if (idx >= 128 * 96 * 96) return;
    int x = idx % 96;
    int y = (idx / 96) % 96;
    int c = idx / (96 * 96);
    float s = 0.f;
#pragma unroll
    for (int dy = 0; dy < 3; ++dy) {
        int yy = y + 1 - dy;
        if (yy < 0 || yy >= 96) continue;
#pragma unroll
        for (int dx = 0; dx < 3; ++dx) {
            int xx = x + 1 - dx;
            if (xx < 0 || xx >= 96) continue;
            int pp = yy * 96 + xx;
            s += R2[(size_t)(c * 9 + dy * 3 + dx) * 9216 + pp] * inv[pp];
        }
    }
    s *= mask[(size_t)(2 * y) * 192 + 2 * x];
    size_t base = (size_t)c * 192 * 192;
    up[base + (size_t)(2 * y) * 192 + 2 * x]         = s;
    up[base + (size_t)(2 * y) * 192 + 2 * x + 1]     = s;
    up[base + (size_t)(2 * y + 1) * 192 + 2 * x]     = s;
    up[base + (size_t)(2 * y + 1) * 192 + 2 * x + 1] = s;
}

// ---------------------------------------------------------------------------
extern "C" void kernel_launch(void* const* d_in, const int* in_sizes, int n_in,
                              void* d_out, int out_size, void* d_ws, size_t ws_size,
                              hipStream_t stream)
{
    const float* x    = (const float*)d_in[0];
    const float* mask = (const float*)d_in[1];
    const float* w[8];
    const float* b[8];
    for (int i = 0; i < 8; ++i) {
        w[i] = (const float*)d_in[2 + 2 * i];
        b[i] = (const float*)d_in[3 + 2 * i];
    }
    char* ws = (char*)d_ws;
    dim3 blk(256);

    // byte offsets (liveness-audited; peak ~169.5 MB)
    const size_t U_H1CL = 0;            // cl bf16 768^2 x32  (37,748,736)
    const size_t U_H2   = 37748736;     // cl bf16 384^2 x32  ( 9,437,184)
    const size_t U_H3   = 47185920;     // cl bf16 384^2 x64  (18,874,368)
    const size_t U_H4   = 66060288;     // cl bf16 192^2 x128 ( 9,437,184)
    const size_t U_H5   = 75497472;
    const size_t U_H6   = 84934656;     // ends 94,371,840
    const size_t U_X4   = 94371840;     // cl bf16 ic4 768^2  ( 4,718,592) [conv1 only]
    const size_t U_FGPT = 0;            // (21,233,664) over dead h1cl
    const size_t U_BGPT = 21233664;     // ends 42,467,328 (h1cl+h2 dead)
    const size_t U_BGPK = 42467328;     // ends 63,700,992 (h2/h3 dead)
    const size_t U_FGPK = 63700992;     // ends 84,934,656 (h4/h5 dead)
    const size_t F_GP   = 94371840;     // 8x1152^2 fp32 (42,467,328) ends 136,839,168 [h6,x4 dead]
    const size_t U_P    = 63700992;     // bf16 9216x3072 (56,623,104) ends 120,324,096 [fgpK,GP dead]
    const size_t F_R2   = 120324096;    // fp32 1152x9216 (42,467,328) ends 162,791,424
    const size_t F_RSP  = 162791424;    // fp32 9216x144 (5,308,416) ends 168,099,840
    const size_t F_INV  = 168099840;    // (36,864) -> 168,136,704
    const size_t U_WP1  = 168136704;    // ( 8,192)
    const size_t U_WP2  = 168144896;    // (18,432)
    const size_t U_WP3  = 168163328;    // (36,864)
    const size_t U_WP4  = 168200192;    // (147,456)
    const size_t U_WP5  = 168347648;    // (294,912)
    const size_t U_WP6  = 168642560;
    const size_t U_WP7  = 168937472;
    const size_t U_WP8  = 169232384;    // ends 169,527,296
    const size_t D_RED  = 169527296;    // (4,096)
    const size_t F_SCALE= 169531392;    // (256) -> 169,531,648 peak
    const size_t F_UP   = 0;            // planar fp32 (18,874,368) [fgpT dead]
    const size_t U_UPCL = 18874368;     // cl bf16 (9,437,184)
    const size_t U_H7   = 28311552;     // cl bf16
    const size_t F_H8   = 37748736;     // cl fp32 (18,874,368) ends 56,623,104 [bgpT/bgpK dead]

    u16* h1cl   = (u16*)(ws + U_H1CL);
    u16* h2     = (u16*)(ws + U_H2);
    u16* h3     = (u16*)(ws + U_H3);
    u16* h4     = (u16*)(ws + U_H4);
    u16* h5     = (u16*)(ws + U_H5);
    u16* h6     = (u16*)(ws + U_H6);
    u16* x4     = (u16*)(ws + U_X4);
    u16* fgpT   = (u16*)(ws + U_FGPT);
    u16* bgpT   = (u16*)(ws + U_BGPT);
    u16* bgpK   = (u16*)(ws + U_BGPK);
    u16* fgpK   = (u16*)(ws + U_FGPK);
    float* GP   = (float*)(ws + F_GP);
    u16* P      = (u16*)(ws + U_P);
    float* R2   = (float*)(ws + F_R2);
    float* rsP  = (float*)(ws + F_RSP);
    float* inv  = (float*)(ws + F_INV);
    u16* wp1    = (u16*)(ws + U_WP1);
    u16* wp2    = (u16*)(ws + U_WP2);
    u16* wp3    = (u16*)(ws + U_WP3);
    u16* wp4    = (u16*)(ws + U_WP4);
    u16* wp5    = (u16*)(ws + U_WP5);
    u16* wp6    = (u16*)(ws + U_WP6);
    u16* wp7    = (u16*)(ws + U_WP7);
    u16* wp8    = (u16*)(ws + U_WP8);
    double* red = (double*)(ws + D_RED);
    float* scale= (float*)(ws + F_SCALE);
    float* upP  = (float*)(ws + F_UP);
    u16* upCL   = (u16*)(ws + U_UPCL);
    u16* h7     = (u16*)(ws + U_H7);
    float* h8   = (float*)(ws + F_H8);

    // ---- prepack ----
    pack_w1_kernel<<<dim3(16), blk, 0, stream>>>(w[0], wp1);
    pack_w_kernel<<<dim3(36),  blk, 0, stream>>>(w[1], wp2, 32, 32);
    pack_w_kernel<<<dim3(72),  blk, 0, stream>>>(w[2], wp3, 64, 32);
    pack_w_kernel<<<dim3(288), blk, 0, stream>>>(w[3], wp4, 128, 64);
    pack_w_kernel<<<dim3(576), blk, 0, stream>>>(w[4], wp5, 128, 128);
    pack_w_kernel<<<dim3(576), blk, 0, stream>>>(w[5], wp6, 128, 128);
    pack_w_kernel<<<dim3(576), blk, 0, stream>>>(w[6], wp7, 128, 128);
    pack_w_kernel<<<dim3(576), blk, 0, stream>>>(w[7], wp8, 128, 128);
    x4cl_kernel<<<dim3(2304), blk, 0, stream>>>(x, x4);

    // ---- conv front-end ----
    conv1_mfma_kernel<<<dim3(48, 96), blk, 0, stream>>>(x4, wp1, b[0], h1cl);
    mfma_conv_kernel<4, 1, 2, 2, 2, 32, 32, 1, 0><<<dim3(24, 48), blk, 0, stream>>>(
        h1cl, wp2, b[1], h2, 768, 768, 384, 384, 32);
    mfma_conv_kernel<4, 2, 2, 2, 1, 32, 32, 1, 0><<<dim3(24, 48), blk, 0, stream>>>(
        h2, wp3, b[2], h3, 384, 384, 384, 384, 64);
    mfma_conv_kernel<4, 2, 2, 2, 2, 64, 32, 1, 0><<<dim3(12, 24, 2), blk, 0, stream>>>(
        h3, wp4, b[3], h4, 384, 384, 192, 192, 128);
    mfma_conv_kernel<4, 2, 2, 2, 1, 128, 128, 1, 0><<<dim3(12, 24, 2), blk, 0, stream>>>(
        h4, wp5, b[4], h5, 192, 192, 192, 192, 128);
    mfma_conv_kernel<4, 2, 2, 2, 1, 128, 128, 0, 0><<<dim3(12, 24, 2), blk, 0, stream>>>(
        h5, wp6, b[5], h6, 192, 192, 192, 192, 128);

    // ---- patch matrices ----
    build_patches_T<<<dim3(41472), blk, 0, stream>>>(h6, mask, fgpT, bgpT);
    build_patches_K<<<dim3(41472), blk, 0, stream>>>(h6, mask, fgpK, bgpK);

    // ---- norm scale via Gram trick ----
    gram_kernel<<<dim3(9, 9, 8), blk, 0, stream>>>(fgpK, bgpK, GP);
    dot_gram_stage1<<<dim3(512), blk, 0, stream>>>(GP, red);
    sumsq_stage2<<<dim3(1), blk, 0, stream>>>(red, 512, scale);

    // ---- 3 q-stripes of 3072: S-exp (fused row-partials) -> P, PV ----
    for (int s = 0; s < 3; ++s) {
        size_t qs = (size_t)s * 3072;
        mfma_nt_kernel<1><<<dim3(24, 72), blk, 0, stream>>>(
            fgpT, bgpT + qs * 1152, 1152, 1152, 1152, nullptr, P, 3072, scale,
            rsP, s * 48);
        if (s == 0)
            mfma_nt_kernel<3><<<dim3(72, 9), blk, 0, stream>>>(
                bgpK + qs, P, 9216, 3072, 3072, R2, nullptr, 9216, nullptr, nullptr, 0);
        else
            mfma_nt_kernel<2><<<dim3(72, 9), blk, 0, stream>>>(
                bgpK + qs, P, 9216, 3072, 3072, R2, nullptr, 9216, nullptr, nullptr, 0);
    }
    inv_kernel<<<dim3(36), blk, 0, stream>>>(rsP, inv);
    fold_mask_up_kernel<<<dim3(4608), blk, 0, stream>>>(R2, inv, mask, upP);

    // ---- back-end convs ----
    p2cl_kernel<<<dim3(1152), blk, 0, stream>>>(upP, upCL);
    mfma_conv_kernel<4, 2, 2, 2, 1, 128, 128, 1, 0><<<dim3(12, 24, 2), blk, 0, stream>>>(
        upCL, wp7, b[6], h7, 192, 192, 192, 192, 128);
    mfma_conv_kernel<4, 2, 2, 2, 1, 128, 128, 1, 1><<<dim3(12, 24, 2), blk, 0, stream>>>(
        h7, wp8, b[7], h8, 192, 192, 192, 192, 128);
    cl2p_kernel<<<dim3(1152), blk, 0, stream>>>(h8, (float*)d_out);
}